// Round 4
// baseline (630.314 us; speedup 1.0000x reference)
//
#include <hip/hip_runtime.h>
#include <hip/hip_fp16.h>
#include <math.h>

#define NREP 16
#define RDIM 16
#define NS   16
#define NC   6
#define H1   144
#define DBINS 64
#define NXCD 8

static __device__ __forceinline__ float leaky(float v) { return v > 0.0f ? v : 0.01f * v; }

// ---- non-temporal (streaming) access helpers: keep single-use streams out of L2 ----
typedef float __attribute__((ext_vector_type(2))) f2_t;
static __device__ __forceinline__ int ntload_i(const int* p) {
  return __builtin_nontemporal_load(p);
}
static __device__ __forceinline__ float2 ntload_f2(const float2* p) {
  f2_t v = __builtin_nontemporal_load((const f2_t*)p);
  return make_float2(v.x, v.y);
}
static __device__ __forceinline__ void ntstore_f2(float2* p, float2 v) {
  f2_t w; w.x = v.x; w.y = v.y;
  __builtin_nontemporal_store(w, (f2_t*)p);
}

// ---------- fused: per-graph mean (LDS-binned) + edge row count ----------
__global__ void k_gsum_count(const float* __restrict__ pos, const int* __restrict__ batch,
                             int N, float* __restrict__ gsum, float* __restrict__ gcnt,
                             const int* __restrict__ ei, int E, int* __restrict__ cnt) {
  int t = threadIdx.x;
  int e = blockIdx.x * 256 + t;
  if (e < E) atomicAdd(&cnt[ntload_i(ei + e)], 1);   // nt: ei is read-once; keep cnt L2-hot

  __shared__ float bx[320], by[320], bc[320];
  int start = blockIdx.x * 256;
  if (start >= N) return;
  int n = start + t;
  int b0 = batch[min(start, N - 1)];
  int span = batch[min(start + 255, N - 1)] - b0;
  bool useLds = (span < 320);
  if (useLds) {
    for (int i = t; i <= span; i += 256) { bx[i] = 0.f; by[i] = 0.f; bc[i] = 0.f; }
    __syncthreads();
    if (n < N) {
      int rb = batch[n] - b0;
      atomicAdd(&bx[rb], pos[2 * n + 0]);
      atomicAdd(&by[rb], pos[2 * n + 1]);
      atomicAdd(&bc[rb], 1.0f);
    }
    __syncthreads();
    for (int i = t; i <= span; i += 256) {
      if (bc[i] != 0.0f) {
        atomicAdd(&gsum[2 * (b0 + i) + 0], bx[i]);
        atomicAdd(&gsum[2 * (b0 + i) + 1], by[i]);
        atomicAdd(&gcnt[b0 + i], bc[i]);
      }
    }
  } else if (n < N) {
    int b = batch[n];
    atomicAdd(&gsum[2 * b + 0], pos[2 * n + 0]);
    atomicAdd(&gsum[2 * b + 1], pos[2 * n + 1]);
    atomicAdd(&gcnt[b], 1.0f);
  }
}

// ---------- fused: center + degree histogram + scan phase 1 ----------
__global__ void k_center_dhist_scan1(
    const float* __restrict__ pos, const int* __restrict__ batch, int N,
    const float* __restrict__ gsum, const float* __restrict__ gcnt,
    float* __restrict__ posc, float* __restrict__ cthn, float* __restrict__ sthn,
    const int* __restrict__ cnt, int* __restrict__ dhist,
    int* __restrict__ off, int* __restrict__ bsum) {
  __shared__ int lh[DBINS];
  __shared__ int sd[1024];
  int t = threadIdx.x;
  int i = blockIdx.x * 1024 + t;
  if (t < DBINS) lh[t] = 0;
  int v = (i < N) ? cnt[i] : 0;
  sd[t] = v;
  if (i < N) {
    int b = batch[i];
    float invc = 1.0f / fmaxf(gcnt[b], 1.0f);
    float px = pos[2 * i + 0] - gsum[2 * b + 0] * invc;
    float py = pos[2 * i + 1] - gsum[2 * b + 1] * invc;
    posc[2 * i + 0] = px;
    posc[2 * i + 1] = py;
    float r = sqrtf(px * px + py * py);
    if (r > 0.0f) { cthn[i] = px / r; sthn[i] = py / r; }
    else          { cthn[i] = 1.0f;  sthn[i] = 0.0f; }
  }
  __syncthreads();
  if (i < N) atomicAdd(&lh[min(v, DBINS - 1)], 1);
  for (int o = 1; o < 1024; o <<= 1) {
    int u = (t >= o) ? sd[t - o] : 0;
    __syncthreads();
    sd[t] += u;
    __syncthreads();
  }
  if (i < N) off[i] = sd[t] - v;
  if (t == 1023) bsum[blockIdx.x] = sd[1023];
  if (t < DBINS && lh[t] > 0) atomicAdd(&dhist[t], lh[t]);
}

// ---------- fused: degree-bin exclusive scan + block-sum exclusive scan ----------
__global__ void k_dscan_scan2(const int* __restrict__ dhist, int* __restrict__ dcur,
                              int* __restrict__ bsum, int nb) {
  __shared__ int s1[DBINS];
  __shared__ int s2[1024];
  int t = threadIdx.x;
  int v1 = (t < DBINS) ? dhist[t] : 0;
  if (t < DBINS) s1[t] = v1;
  int v2 = (t < nb) ? bsum[t] : 0;
  s2[t] = v2;
  __syncthreads();
  for (int o = 1; o < 1024; o <<= 1) {
    int u1 = (o < DBINS && t >= o && t < DBINS) ? s1[t - o] : 0;
    int u2 = (t >= o) ? s2[t - o] : 0;
    __syncthreads();
    if (o < DBINS && t < DBINS) s1[t] += u1;
    s2[t] += u2;
    __syncthreads();
  }
  if (t < DBINS) dcur[t] = s1[t] - v1;
  if (t < nb) bsum[t] = s2[t] - v2;
}

// ---------- fused: scan phase 3 + degree-sort fill + cursor=off init ----------
__global__ void k_dfill_scan3(int* __restrict__ off, const int* __restrict__ bsum,
                              int N, int E,
                              const int* __restrict__ cnt, int* __restrict__ dcur,
                              int* __restrict__ perm, int* __restrict__ cursor) {
  int t = threadIdx.x;
  int i = blockIdx.x * 1024 + t;
  if (i < N) {
    int ov = off[i] + bsum[blockIdx.x];
    off[i] = ov;
    cursor[i] = ov;                     // k_scatter slots start at off[i]
  }
  if (i == N) off[N] = E;

  __shared__ int lh[DBINS];
  __shared__ int base[DBINS];
  if (t < DBINS) lh[t] = 0;
  __syncthreads();
  int b = 0, lr = 0;
  if (i < N) {
    b = min(cnt[i], DBINS - 1);
    lr = atomicAdd(&lh[b], 1);
  }
  __syncthreads();
  if (t < DBINS && lh[t] > 0) base[t] = atomicAdd(&dcur[t], lh[t]);
  __syncthreads();
  if (i < N) perm[base[b] + lr] = i;
}

// ---------- XCD-partitioned adjacency scatter with nt ei reads ----------
// Round-3 post-mortem: partitioning alone left ~1 writeback per store because the 12.8MB
// ei stream THRASHES the 4MB XCD L2, evicting partially-filled adj lines between their
// ~16 stores. nt loads keep the stream out of L2 -> adj (800KB) + cursor (50KB) stay
// resident -> each adj line accumulates all stores locally and writes back once.
__global__ void __launch_bounds__(256) k_scatter8(
    const int* __restrict__ ei, int E, int N,
    int* __restrict__ cursor, int* __restrict__ adj) {
  int part = blockIdx.x & (NXCD - 1);
  int e = (blockIdx.x >> 3) * 256 + threadIdx.x;
  if (e >= E) return;
  int lo = (int)((long long)part * N / NXCD);
  int hi = (int)((long long)(part + 1) * N / NXCD);
  int r = ntload_i(ei + e);
  if (r < lo || r >= hi) return;
  int cl = ntload_i(ei + E + e);
  int p = atomicAdd(&cursor[r], 1);
  adj[p] = cl;
}

// ---------- fused node init + per-edge trig fill + layer-0 pre ----------
// 16 lanes/node; lane r owns edges k=a+r, a+r+16, ... so each edge's sincospif is
// computed exactly once, and spc[k] writes are lane-consecutive (coalesced 128B/group).
__global__ void __launch_bounds__(256) k_init16(
    int N, const int* __restrict__ off, const int* __restrict__ adj,
    const float* __restrict__ posc, float2* __restrict__ spc,
    const float* __restrict__ Wer, const float* __restrict__ wse, const float* __restrict__ bse,
    const float* __restrict__ Wmix, const float* __restrict__ Ws1, const float* __restrict__ bs1,
    const float* __restrict__ Wgate, const float* __restrict__ bgate,
    float* __restrict__ xr, float* __restrict__ xs, uint2* __restrict__ yzg) {
  int idx = blockIdx.x * 256 + threadIdx.x;
  int n = idx >> 4, r = idx & 15;
  if (n >= N) return;
  int a = off[n], b = off[n + 1];
  float px = posc[2 * n + 0], py = posc[2 * n + 1];
  float C = 0.f, S = 0.f, D = 0.f;
  for (int k = a + r; k < b; k += 16) {
    int cl = ntload_i(adj + k);              // nt: adj read-once here; keep posc cached
    float dx = px - posc[2 * cl + 0];
    float dy = py - posc[2 * cl + 1];
    float d = sqrtf(dx * dx + dy * dy);
    float sp, cp;
    sincospif(d, &sp, &cp);
    float spp = 1.41421356237309515f * sp / (d + 1e-8f);
    ntstore_f2(&spc[k], make_float2(spp, 2.0f * cp));   // nt: streamed, consumed next kernel
    if (d > 0.0f) {
      float inv = 1.0f / d;
      C += dx * inv;
      S += dy * inv;
    } else {
      C += 1.0f;
    }
    D += d;
  }
#pragma unroll
  for (int o = 1; o < 16; o <<= 1) {         // butterfly: all 16 lanes get full sums
    C += __shfl_xor(C, o, 16);
    S += __shfl_xor(S, o, 16);
    D += __shfl_xor(D, o, 16);
  }
  float id = 1.0f / fmaxf((float)(b - a), 1.0f);
  C *= id; S *= id;
  float dm = D * id;
  float w0 = Wer[2 * r], w1 = Wer[2 * r + 1];
  float2 x;
  x.x = C * w0 - S * w1;
  x.y = S * w0 + C * w1;
  ((float2*)xr)[(size_t)n * 16 + r] = x;
  float s_new = leaky(dm * wse[r] + bse[r]);
  xs[(size_t)n * 16 + r] = s_new;

  // fused layer-0 pre (shuffle form — same pattern as k_layer's write_next tail)
  float wmxn[16], wsan[16], wgtn[16];
#pragma unroll
  for (int q = 0; q < 16; q++) wmxn[q] = Wmix[r * 16 + q];
#pragma unroll
  for (int q = 0; q < 16; q++) wsan[q] = Ws1[q * 16 + r];
#pragma unroll
  for (int q = 0; q < 16; q++) wgtn[q] = Wgate[q * 16 + r];
  float y0 = 0.f, y1 = 0.f;
  float z = bs1[r], gtn = bgate[r];
#pragma unroll
  for (int j = 0; j < 16; j++) {
    float xj0 = __shfl(x.x, j, 16);
    float xj1 = __shfl(x.y, j, 16);
    float sj  = __shfl(s_new, j, 16);
    y0 += wmxn[j] * xj0;
    y1 += wmxn[j] * xj1;
    z  += wsan[j] * sj;
    gtn += wgtn[j] * sj;
  }
  gtn = 1.0f / (1.0f + __expf(-gtn));
  __half2 hA = __floats2half2_rn(y0, y1);
  __half2 hB = __floats2half2_rn(z, gtn);
  uint2 w2;
  w2.x = *(unsigned int*)&hA;
  w2.y = *(unsigned int*)&hB;
  yzg[(size_t)n * 16 + r] = w2;
}

// ---------- EqBlock layer + fused next-layer pre (peeled prefetch, SoA adj+spc, nt streams) ----------
__global__ void __launch_bounds__(256) k_layer(
    int N, const int* __restrict__ off,
    const int* __restrict__ adj, const float2* __restrict__ spc,
    const uint2* __restrict__ yzg, const int* __restrict__ perm,
    const float* __restrict__ Wg, const float* __restrict__ bg,
    const float* __restrict__ Ws1,   // this layer; demb rows are 16..31
    float* xr, float* xs,
    int write_next, uint2* __restrict__ yzg_out,
    const float* __restrict__ Wmixn, const float* __restrict__ Ws1n,
    const float* __restrict__ bs1n,
    const float* __restrict__ Wgaten, const float* __restrict__ bgaten) {
  int idx = blockIdx.x * 256 + threadIdx.x;
  int g = idx >> 4, r = idx & 15;
  if (g >= N) return;
  int n = perm[g];                      // degree-sorted: waves get equal-degree nodes
  float wg[16], ws[16];
#pragma unroll
  for (int q = 0; q < 16; q++) wg[q] = Wg[q * 16 + r];
#pragma unroll
  for (int q = 0; q < 16; q++) ws[q] = Ws1[(16 + q) * 16 + r];
  float bgr = bg[r];

  int a = off[n], bnd = off[n + 1];
  float acc0 = 0.f, acc1 = 0.f, accs = 0.f;
  if (a < bnd) {
    int last = bnd - 1;
    // nt: adj/spc are read-once streams; reserve L2 for the yzg gather footprint (12.8MB)
    int    c0 = ntload_i(adj + a);               float2 p0 = ntload_f2(spc + a);
    int    c1 = ntload_i(adj + min(a + 1, last)); float2 p1 = ntload_f2(spc + min(a + 1, last));
    int    cn = ntload_i(adj + min(a + 2, last)); float2 p2 = ntload_f2(spc + min(a + 2, last));
    uint2 Y0 = yzg[(c0 << 4) + r];
    uint2 Y1 = yzg[(c1 << 4) + r];
    int k = a;
    // main loop: all prefetches provably in-range (no clamps)
    for (; k + 3 < bnd; k++) {
      int c3 = ntload_i(adj + k + 3);
      float2 p3 = ntload_f2(spc + k + 3);
      uint2 Y2 = yzg[(cn << 4) + r];
      float skm1 = 0.f, sk = p0.x, c2 = p0.y;
      float g1 = bgr, dot = 0.f;
#pragma unroll
      for (int q = 0; q < RDIM; q++) {
        g1  = __builtin_fmaf(sk, wg[q], g1);
        dot = __builtin_fmaf(sk, ws[q], dot);
        float sn = __builtin_fmaf(c2, sk, -skm1);
        skm1 = sk; sk = sn;
      }
      float2 f01 = __half22float2(*(__half2*)&Y0.x);
      float2 fzg = __half22float2(*(__half2*)&Y0.y);
      acc0 = __builtin_fmaf(g1, f01.x, acc0);
      acc1 = __builtin_fmaf(g1, f01.y, acc1);
      accs += leaky(dot + fzg.x);
      c0 = c1; p0 = p1; c1 = cn; p1 = p2; cn = c3; p2 = p3; Y0 = Y1; Y1 = Y2;
    }
    // tail (<=3 iterations): registers already hold the remaining edges
    for (; k < bnd; k++) {
      uint2 Y2 = Y1;
      if (k + 2 < bnd) Y2 = yzg[(cn << 4) + r];
      float skm1 = 0.f, sk = p0.x, c2 = p0.y;
      float g1 = bgr, dot = 0.f;
#pragma unroll
      for (int q = 0; q < RDIM; q++) {
        g1  = __builtin_fmaf(sk, wg[q], g1);
        dot = __builtin_fmaf(sk, ws[q], dot);
        float sn = __builtin_fmaf(c2, sk, -skm1);
        skm1 = sk; sk = sn;
      }
      float2 f01 = __half22float2(*(__half2*)&Y0.x);
      float2 fzg = __half22float2(*(__half2*)&Y0.y);
      acc0 = __builtin_fmaf(g1, f01.x, acc0);
      acc1 = __builtin_fmaf(g1, f01.y, acc1);
      accs += leaky(dot + fzg.x);
      c0 = c1; p0 = p1; c1 = cn; p1 = p2; Y0 = Y1; Y1 = Y2;
    }
  }
  float id = 1.0f / fmaxf((float)(bnd - a), 1.0f);
  uint2 Yg = yzg[(n << 4) + r];
  float gt = __half22float2(*(__half2*)&Yg.y).y;
  float2* xr2 = (float2*)xr;
  float2 x = xr2[(n << 4) + r];
  x.x += acc0 * id * gt;
  x.y += acc1 * id * gt;
  xr2[(n << 4) + r] = x;                // in-place safe: (n,r) written only by this thread
  float s_new = xs[(n << 4) + r] + accs * id;
  xs[(n << 4) + r] = s_new;

  if (write_next) {
    // fused k_pre for next layer: cross-r via 16-wide shuffles (same sum order as k_pre)
    float wmxn[16], wsan[16], wgtn[16];
#pragma unroll
    for (int q = 0; q < 16; q++) wmxn[q] = Wmixn[r * 16 + q];
#pragma unroll
    for (int q = 0; q < 16; q++) wsan[q] = Ws1n[q * 16 + r];
#pragma unroll
    for (int q = 0; q < 16; q++) wgtn[q] = Wgaten[q * 16 + r];
    float y0 = 0.f, y1 = 0.f;
    float z = bs1n[r], gtn = bgaten[r];
#pragma unroll
    for (int j = 0; j < 16; j++) {
      float xj0 = __shfl(x.x, j, 16);
      float xj1 = __shfl(x.y, j, 16);
      float sj  = __shfl(s_new, j, 16);
      y0 += wmxn[j] * xj0;
      y1 += wmxn[j] * xj1;
      z  += wsan[j] * sj;
      gtn += wgtn[j] * sj;
    }
    gtn = 1.0f / (1.0f + __expf(-gtn));
    __half2 hA = __floats2half2_rn(y0, y1);
    __half2 hB = __floats2half2_rn(z, gtn);
    uint2 w2;
    w2.x = *(unsigned int*)&hA;
    w2.y = *(unsigned int*)&hB;
    yzg_out[(n << 4) + r] = w2;
  }
}

// ---------- final rotate-out + MLP (wave-uniform scalar weight loads) + binned graph sum ----------
__global__ void __launch_bounds__(128) k_final(
    int N, const float* __restrict__ xr, const float* __restrict__ xs,
    const float* __restrict__ cthn, const float* __restrict__ sthn,
    const int* __restrict__ batch,
    const float* __restrict__ W1, const float* __restrict__ b1,
    const float* __restrict__ W2, const float* __restrict__ b2,
    float* __restrict__ out) {
  __shared__ float obin[320 * 6];
  int t = threadIdx.x;
  int start = blockIdx.x * 128;
  int n = start + t;
  int b0 = batch[min(start, N - 1)];
  int span = batch[min(start + 127, N - 1)] - b0;
  bool useLds = (span < 320);
  if (useLds) for (int i = t; i < (span + 1) * 6; i += 128) obin[i] = 0.f;
  __syncthreads();

  float u[NC];
  bool act = (n < N);
  if (act) {
    float xc[48];
    const float4* xs4 = (const float4*)(xs + (size_t)n * NS);
#pragma unroll
    for (int j = 0; j < 4; j++) {
      float4 v = xs4[j];
      xc[4 * j + 0] = v.x; xc[4 * j + 1] = v.y; xc[4 * j + 2] = v.z; xc[4 * j + 3] = v.w;
    }
    float c = cthn[n], s = sthn[n];
    const float4* xr4 = (const float4*)(xr + (size_t)n * 32);
#pragma unroll
    for (int j = 0; j < 8; j++) {
      float4 v = xr4[j];
      xc[16 + 4 * j + 0] = c * v.x - s * v.y;
      xc[16 + 4 * j + 1] = s * v.x + c * v.y;
      xc[16 + 4 * j + 2] = c * v.z - s * v.w;
      xc[16 + 4 * j + 3] = s * v.z + c * v.w;
    }
#pragma unroll
    for (int q = 0; q < NC; q++) u[q] = b2[q];
    for (int h = 0; h < H1; h += 4) {
      float a0 = b1[h + 0], a1 = b1[h + 1], a2 = b1[h + 2], a3 = b1[h + 3];
#pragma unroll
      for (int q = 0; q < 48; q++) {
        // uniform address (h,q uniform) -> s_load_dwordx4, cached in K$/L1
        float4 w = *(const float4*)(W1 + (size_t)q * H1 + h);
        float x = xc[q];
        a0 = __builtin_fmaf(x, w.x, a0);
        a1 = __builtin_fmaf(x, w.y, a1);
        a2 = __builtin_fmaf(x, w.z, a2);
        a3 = __builtin_fmaf(x, w.w, a3);
      }
      a0 = leaky(a0); a1 = leaky(a1); a2 = leaky(a2); a3 = leaky(a3);
#pragma unroll
      for (int q = 0; q < NC; q++)
        u[q] += a0 * W2[(h + 0) * 6 + q] + a1 * W2[(h + 1) * 6 + q]
              + a2 * W2[(h + 2) * 6 + q] + a3 * W2[(h + 3) * 6 + q];
    }
  }
  if (useLds) {
    if (act) {
      int rb = batch[n] - b0;
#pragma unroll
      for (int q = 0; q < NC; q++) atomicAdd(&obin[rb * 6 + q], u[q]);
    }
    __syncthreads();
    for (int i = t; i < (span + 1) * 6; i += 128) atomicAdd(&out[b0 * 6 + i], obin[i]);
  } else if (act) {
    int b = batch[n];
#pragma unroll
    for (int q = 0; q < NC; q++) atomicAdd(&out[b * 6 + q], u[q]);
  }
}

extern "C" void kernel_launch(void* const* d_in, const int* in_sizes, int n_in,
                              void* d_out, int out_size, void* d_ws, size_t ws_size,
                              hipStream_t stream) {
  const float* pos   = (const float*)d_in[0];
  const float* Wer   = (const float*)d_in[1];
  const float* wse   = (const float*)d_in[2];
  const float* bse   = (const float*)d_in[3];
  const float* Wg    = (const float*)d_in[4];
  const float* bg    = (const float*)d_in[5];
  const float* Wmix  = (const float*)d_in[6];
  const float* Wgate = (const float*)d_in[7];
  const float* bgate = (const float*)d_in[8];
  const float* Ws1   = (const float*)d_in[9];
  const float* bs1   = (const float*)d_in[10];
  const float* W1    = (const float*)d_in[11];
  const float* b1    = (const float*)d_in[12];
  const float* W2    = (const float*)d_in[13];
  const float* b2    = (const float*)d_in[14];
  const int*   ei    = (const int*)d_in[15];
  const int*   batch = (const int*)d_in[16];
  float* out = (float*)d_out;

  int N = in_sizes[0] / 2;
  int E = in_sizes[15] / 2;
  int G = out_size / NC;

  // ---- workspace layout (~55 MB for N=100k, E=1.6M) ----
  float* W = (float*)d_ws;
  size_t o = 0;
  float* gsum   = W + o; o += (size_t)2 * G;
  float* gcnt   = W + o; o += (size_t)G;
  int*   cnt    = (int*)(W + o); o += (size_t)N;
  int*   cursor = (int*)(W + o); o += (size_t)N;
  int*   dhist  = (int*)(W + o); o += (size_t)DBINS;
  size_t zero_bytes = o * 4;
  o = (o + 3) & ~(size_t)3;
  float* posc   = W + o; o += (size_t)2 * N;
  float* cthn   = W + o; o += (size_t)N;
  float* sthn   = W + o; o += (size_t)N;
  int*   off    = (int*)(W + o); o += (size_t)N + 1; o = (o + 3) & ~(size_t)3;
  int*   bsum   = (int*)(W + o); o += (size_t)1024;
  int*   dcur   = (int*)(W + o); o += (size_t)DBINS;
  int*   perm   = (int*)(W + o); o += (size_t)N; o = (o + 3) & ~(size_t)3;
  int*   adj    = (int*)(W + o); o += (size_t)E; o = (o + 1) & ~(size_t)1;
  float2* spc   = (float2*)(W + o); o += (size_t)2 * E;
  uint2* yzgA   = (uint2*)(W + o); o += (size_t)32 * N;
  uint2* yzgB   = (uint2*)(W + o); o += (size_t)32 * N;
  float* xr     = W + o; o += (size_t)N * 32;
  float* xs     = W + o; o += (size_t)N * 16;
  (void)ws_size;

  hipMemsetAsync(d_ws, 0, zero_bytes, stream);
  hipMemsetAsync(d_out, 0, (size_t)out_size * 4, stream);

  int nbN  = (N + 255) / 256;
  int nbE  = (E + 255) / 256;
  int nbE8 = NXCD * ((E + 255) / 256);
  int nbN16 = ((size_t)N * 16 + 255) / 256;
  int nbS  = (N + 1023) / 1024;
  int nbS3 = (N + 1 + 1023) / 1024;
  int nbF  = (N + 127) / 128;

  k_gsum_count<<<nbE, 256, 0, stream>>>(pos, batch, N, gsum, gcnt, ei, E, cnt);
  k_center_dhist_scan1<<<nbS, 1024, 0, stream>>>(pos, batch, N, gsum, gcnt,
                                                 posc, cthn, sthn, cnt, dhist, off, bsum);
  k_dscan_scan2<<<1, 1024, 0, stream>>>(dhist, dcur, bsum, nbS);
  k_dfill_scan3<<<nbS3, 1024, 0, stream>>>(off, bsum, N, E, cnt, dcur, perm, cursor);
  k_scatter8<<<nbE8, 256, 0, stream>>>(ei, E, N, cursor, adj);
  k_init16<<<nbN16, 256, 0, stream>>>(N, off, adj, posc, spc, Wer, wse, bse,
                                      Wmix, Ws1, bs1, Wgate, bgate,
                                      xr, xs, yzgA);

  // layer 0: read A, write B (fused pre for layer 1)
  k_layer<<<nbN16, 256, 0, stream>>>(N, off, adj, spc, yzgA, perm,
                                     Wg, bg, Ws1, xr, xs,
                                     1, yzgB,
                                     Wmix + 256, Ws1 + 512, bs1 + 16, Wgate + 256, bgate + 16);
  // layer 1: read B, write A (fused pre for layer 2)
  k_layer<<<nbN16, 256, 0, stream>>>(N, off, adj, spc, yzgB, perm,
                                     Wg + 256, bg + 16, Ws1 + 512, xr, xs,
                                     1, yzgA,
                                     Wmix + 512, Ws1 + 1024, bs1 + 32, Wgate + 512, bgate + 32);
  // layer 2: read A, no next
  k_layer<<<nbN16, 256, 0, stream>>>(N, off, adj, spc, yzgA, perm,
                                     Wg + 512, bg + 32, Ws1 + 1024, xr, xs,
                                     0, yzgB,
                                     Wmix, Ws1, bs1, Wgate, bgate);

  k_final<<<nbF, 128, 0, stream>>>(N, xr, xs, cthn, sthn, batch, W1, b1, W2, b2, out);
}

// Round 5
// 532.541 us; speedup vs baseline: 1.1836x; 1.1836x over previous
//
#include <hip/hip_runtime.h>
#include <hip/hip_fp16.h>
#include <math.h>

#define NREP 16
#define RDIM 16
#define NS   16
#define NC   6
#define H1   144
#define DBINS 64
#define NXCD 8

static __device__ __forceinline__ float leaky(float v) { return v > 0.0f ? v : 0.01f * v; }

// nt load for streams whose lines are fully consumed by a single wave instruction
// (coalesced lane-consecutive reads). Do NOT use on broadcast/serial-iteration streams
// (round-4 lesson: k_layer adj/spc lines are consumed over ~16 iterations -> nt = +100MB).
static __device__ __forceinline__ int ntload_i(const int* p) {
  return __builtin_nontemporal_load(p);
}

// ---------- fused: per-graph mean (LDS-binned) + XCD-partitioned edge row count ----------
// Histogram partitioned like k_scatter8: block b counts only rows in partition b&7, so all
// atomics to a given cnt line come from ONE XCD's L2 (no cross-XCD line ping-pong).
// Cost: 8x redundant ei row reads (51MB, L3-served, nt). Node-mean part runs on blocks < nbN.
__global__ void __launch_bounds__(256) k_gsum_count(
    const float* __restrict__ pos, const int* __restrict__ batch,
    int N, float* __restrict__ gsum, float* __restrict__ gcnt,
    const int* __restrict__ ei, int E, int* __restrict__ cnt) {
  int t = threadIdx.x;
  int part = blockIdx.x & (NXCD - 1);
  int e = (blockIdx.x >> 3) * 256 + t;
  if (e < E) {
    int r = ntload_i(ei + e);
    int lo = (int)((long long)part * N / NXCD);
    int hi = (int)((long long)(part + 1) * N / NXCD);
    if (r >= lo && r < hi) atomicAdd(&cnt[r], 1);
  }

  __shared__ float bx[320], by[320], bc[320];
  int start = blockIdx.x * 256;
  if (start >= N) return;
  int n = start + t;
  int b0 = batch[min(start, N - 1)];
  int span = batch[min(start + 255, N - 1)] - b0;
  bool useLds = (span < 320);
  if (useLds) {
    for (int i = t; i <= span; i += 256) { bx[i] = 0.f; by[i] = 0.f; bc[i] = 0.f; }
    __syncthreads();
    if (n < N) {
      int rb = batch[n] - b0;
      atomicAdd(&bx[rb], pos[2 * n + 0]);
      atomicAdd(&by[rb], pos[2 * n + 1]);
      atomicAdd(&bc[rb], 1.0f);
    }
    __syncthreads();
    for (int i = t; i <= span; i += 256) {
      if (bc[i] != 0.0f) {
        atomicAdd(&gsum[2 * (b0 + i) + 0], bx[i]);
        atomicAdd(&gsum[2 * (b0 + i) + 1], by[i]);
        atomicAdd(&gcnt[b0 + i], bc[i]);
      }
    }
  } else if (n < N) {
    int b = batch[n];
    atomicAdd(&gsum[2 * b + 0], pos[2 * n + 0]);
    atomicAdd(&gsum[2 * b + 1], pos[2 * n + 1]);
    atomicAdd(&gcnt[b], 1.0f);
  }
}

// ---------- fused: center + degree histogram + scan phase 1 ----------
__global__ void k_center_dhist_scan1(
    const float* __restrict__ pos, const int* __restrict__ batch, int N,
    const float* __restrict__ gsum, const float* __restrict__ gcnt,
    float* __restrict__ posc, float* __restrict__ cthn, float* __restrict__ sthn,
    const int* __restrict__ cnt, int* __restrict__ dhist,
    int* __restrict__ off, int* __restrict__ bsum) {
  __shared__ int lh[DBINS];
  __shared__ int sd[1024];
  int t = threadIdx.x;
  int i = blockIdx.x * 1024 + t;
  if (t < DBINS) lh[t] = 0;
  int v = (i < N) ? cnt[i] : 0;
  sd[t] = v;
  if (i < N) {
    int b = batch[i];
    float invc = 1.0f / fmaxf(gcnt[b], 1.0f);
    float px = pos[2 * i + 0] - gsum[2 * b + 0] * invc;
    float py = pos[2 * i + 1] - gsum[2 * b + 1] * invc;
    posc[2 * i + 0] = px;
    posc[2 * i + 1] = py;
    float r = sqrtf(px * px + py * py);
    if (r > 0.0f) { cthn[i] = px / r; sthn[i] = py / r; }
    else          { cthn[i] = 1.0f;  sthn[i] = 0.0f; }
  }
  __syncthreads();
  if (i < N) atomicAdd(&lh[min(v, DBINS - 1)], 1);
  for (int o = 1; o < 1024; o <<= 1) {
    int u = (t >= o) ? sd[t - o] : 0;
    __syncthreads();
    sd[t] += u;
    __syncthreads();
  }
  if (i < N) off[i] = sd[t] - v;
  if (t == 1023) bsum[blockIdx.x] = sd[1023];
  if (t < DBINS && lh[t] > 0) atomicAdd(&dhist[t], lh[t]);
}

// ---------- fused: degree-bin exclusive scan + block-sum exclusive scan ----------
__global__ void k_dscan_scan2(const int* __restrict__ dhist, int* __restrict__ dcur,
                              int* __restrict__ bsum, int nb) {
  __shared__ int s1[DBINS];
  __shared__ int s2[1024];
  int t = threadIdx.x;
  int v1 = (t < DBINS) ? dhist[t] : 0;
  if (t < DBINS) s1[t] = v1;
  int v2 = (t < nb) ? bsum[t] : 0;
  s2[t] = v2;
  __syncthreads();
  for (int o = 1; o < 1024; o <<= 1) {
    int u1 = (o < DBINS && t >= o && t < DBINS) ? s1[t - o] : 0;
    int u2 = (t >= o) ? s2[t - o] : 0;
    __syncthreads();
    if (o < DBINS && t < DBINS) s1[t] += u1;
    s2[t] += u2;
    __syncthreads();
  }
  if (t < DBINS) dcur[t] = s1[t] - v1;
  if (t < nb) bsum[t] = s2[t] - v2;
}

// ---------- fused: scan phase 3 + degree-sort fill + cursor=off init ----------
__global__ void k_dfill_scan3(int* __restrict__ off, const int* __restrict__ bsum,
                              int N, int E,
                              const int* __restrict__ cnt, int* __restrict__ dcur,
                              int* __restrict__ perm, int* __restrict__ cursor) {
  int t = threadIdx.x;
  int i = blockIdx.x * 1024 + t;
  if (i < N) {
    int ov = off[i] + bsum[blockIdx.x];
    off[i] = ov;
    cursor[i] = ov;                     // k_scatter slots start at off[i]
  }
  if (i == N) off[N] = E;

  __shared__ int lh[DBINS];
  __shared__ int base[DBINS];
  if (t < DBINS) lh[t] = 0;
  __syncthreads();
  int b = 0, lr = 0;
  if (i < N) {
    b = min(cnt[i], DBINS - 1);
    lr = atomicAdd(&lh[b], 1);
  }
  __syncthreads();
  if (t < DBINS && lh[t] > 0) base[t] = atomicAdd(&dcur[t], lh[t]);
  __syncthreads();
  if (i < N) perm[base[b] + lr] = i;
}

// ---------- XCD-partitioned adjacency scatter (round-3 proven form, no nt) ----------
__global__ void __launch_bounds__(256) k_scatter8(
    const int* __restrict__ ei, int E, int N,
    int* __restrict__ cursor, int* __restrict__ adj) {
  int part = blockIdx.x & (NXCD - 1);
  int e = (blockIdx.x >> 3) * 256 + threadIdx.x;
  if (e >= E) return;
  int lo = (int)((long long)part * N / NXCD);
  int hi = (int)((long long)(part + 1) * N / NXCD);
  int r = ei[e];
  if (r < lo || r >= hi) return;
  int cl = ei[E + e];
  int p = atomicAdd(&cursor[r], 1);
  adj[p] = cl;
}

// ---------- fused node init + per-edge trig fill + layer-0 pre ----------
// 16 lanes/node; lane r owns edges k=a+r, a+r+16, ... so each edge's sincospif is
// computed exactly once, and spc[k] writes are lane-consecutive (coalesced 128B/group).
__global__ void __launch_bounds__(256) k_init16(
    int N, const int* __restrict__ off, const int* __restrict__ adj,
    const float* __restrict__ posc, float2* __restrict__ spc,
    const float* __restrict__ Wer, const float* __restrict__ wse, const float* __restrict__ bse,
    const float* __restrict__ Wmix, const float* __restrict__ Ws1, const float* __restrict__ bs1,
    const float* __restrict__ Wgate, const float* __restrict__ bgate,
    float* __restrict__ xr, float* __restrict__ xs, uint2* __restrict__ yzg) {
  int idx = blockIdx.x * 256 + threadIdx.x;
  int n = idx >> 4, r = idx & 15;
  if (n >= N) return;
  int a = off[n], b = off[n + 1];
  float px = posc[2 * n + 0], py = posc[2 * n + 1];
  float C = 0.f, S = 0.f, D = 0.f;
  for (int k = a + r; k < b; k += 16) {
    int cl = adj[k];
    float dx = px - posc[2 * cl + 0];
    float dy = py - posc[2 * cl + 1];
    float d = sqrtf(dx * dx + dy * dy);
    float sp, cp;
    sincospif(d, &sp, &cp);
    float spp = 1.41421356237309515f * sp / (d + 1e-8f);
    spc[k] = make_float2(spp, 2.0f * cp);
    if (d > 0.0f) {
      float inv = 1.0f / d;
      C += dx * inv;
      S += dy * inv;
    } else {
      C += 1.0f;
    }
    D += d;
  }
#pragma unroll
  for (int o = 1; o < 16; o <<= 1) {         // butterfly: all 16 lanes get full sums
    C += __shfl_xor(C, o, 16);
    S += __shfl_xor(S, o, 16);
    D += __shfl_xor(D, o, 16);
  }
  float id = 1.0f / fmaxf((float)(b - a), 1.0f);
  C *= id; S *= id;
  float dm = D * id;
  float w0 = Wer[2 * r], w1 = Wer[2 * r + 1];
  float2 x;
  x.x = C * w0 - S * w1;
  x.y = S * w0 + C * w1;
  ((float2*)xr)[(size_t)n * 16 + r] = x;
  float s_new = leaky(dm * wse[r] + bse[r]);
  xs[(size_t)n * 16 + r] = s_new;

  // fused layer-0 pre (shuffle form — same pattern as k_layer's write_next tail)
  float wmxn[16], wsan[16], wgtn[16];
#pragma unroll
  for (int q = 0; q < 16; q++) wmxn[q] = Wmix[r * 16 + q];
#pragma unroll
  for (int q = 0; q < 16; q++) wsan[q] = Ws1[q * 16 + r];
#pragma unroll
  for (int q = 0; q < 16; q++) wgtn[q] = Wgate[q * 16 + r];
  float y0 = 0.f, y1 = 0.f;
  float z = bs1[r], gtn = bgate[r];
#pragma unroll
  for (int j = 0; j < 16; j++) {
    float xj0 = __shfl(x.x, j, 16);
    float xj1 = __shfl(x.y, j, 16);
    float sj  = __shfl(s_new, j, 16);
    y0 += wmxn[j] * xj0;
    y1 += wmxn[j] * xj1;
    z  += wsan[j] * sj;
    gtn += wgtn[j] * sj;
  }
  gtn = 1.0f / (1.0f + __expf(-gtn));
  __half2 hA = __floats2half2_rn(y0, y1);
  __half2 hB = __floats2half2_rn(z, gtn);
  uint2 w2;
  w2.x = *(unsigned int*)&hA;
  w2.y = *(unsigned int*)&hB;
  yzg[(size_t)n * 16 + r] = w2;
}

// ---------- EqBlock layer + fused next-layer pre (peeled prefetch, SoA adj+spc) ----------
__global__ void __launch_bounds__(256) k_layer(
    int N, const int* __restrict__ off,
    const int* __restrict__ adj, const float2* __restrict__ spc,
    const uint2* __restrict__ yzg, const int* __restrict__ perm,
    const float* __restrict__ Wg, const float* __restrict__ bg,
    const float* __restrict__ Ws1,   // this layer; demb rows are 16..31
    float* xr, float* xs,
    int write_next, uint2* __restrict__ yzg_out,
    const float* __restrict__ Wmixn, const float* __restrict__ Ws1n,
    const float* __restrict__ bs1n,
    const float* __restrict__ Wgaten, const float* __restrict__ bgaten) {
  int idx = blockIdx.x * 256 + threadIdx.x;
  int g = idx >> 4, r = idx & 15;
  if (g >= N) return;
  int n = perm[g];                      // degree-sorted: waves get equal-degree nodes
  float wg[16], ws[16];
#pragma unroll
  for (int q = 0; q < 16; q++) wg[q] = Wg[q * 16 + r];
#pragma unroll
  for (int q = 0; q < 16; q++) ws[q] = Ws1[(16 + q) * 16 + r];
  float bgr = bg[r];

  int a = off[n], bnd = off[n + 1];
  float acc0 = 0.f, acc1 = 0.f, accs = 0.f;
  if (a < bnd) {
    int last = bnd - 1;
    int    c0 = adj[a];               float2 p0 = spc[a];
    int    c1 = adj[min(a + 1, last)]; float2 p1 = spc[min(a + 1, last)];
    int    cn = adj[min(a + 2, last)]; float2 p2 = spc[min(a + 2, last)];
    uint2 Y0 = yzg[(c0 << 4) + r];
    uint2 Y1 = yzg[(c1 << 4) + r];
    int k = a;
    // main loop: all prefetches provably in-range (no clamps)
    for (; k + 3 < bnd; k++) {
      int c3 = adj[k + 3];
      float2 p3 = spc[k + 3];
      uint2 Y2 = yzg[(cn << 4) + r];
      float skm1 = 0.f, sk = p0.x, c2 = p0.y;
      float g1 = bgr, dot = 0.f;
#pragma unroll
      for (int q = 0; q < RDIM; q++) {
        g1  = __builtin_fmaf(sk, wg[q], g1);
        dot = __builtin_fmaf(sk, ws[q], dot);
        float sn = __builtin_fmaf(c2, sk, -skm1);
        skm1 = sk; sk = sn;
      }
      float2 f01 = __half22float2(*(__half2*)&Y0.x);
      float2 fzg = __half22float2(*(__half2*)&Y0.y);
      acc0 = __builtin_fmaf(g1, f01.x, acc0);
      acc1 = __builtin_fmaf(g1, f01.y, acc1);
      accs += leaky(dot + fzg.x);
      c0 = c1; p0 = p1; c1 = cn; p1 = p2; cn = c3; p2 = p3; Y0 = Y1; Y1 = Y2;
    }
    // tail (<=3 iterations): registers already hold the remaining edges
    for (; k < bnd; k++) {
      uint2 Y2 = Y1;
      if (k + 2 < bnd) Y2 = yzg[(cn << 4) + r];
      float skm1 = 0.f, sk = p0.x, c2 = p0.y;
      float g1 = bgr, dot = 0.f;
#pragma unroll
      for (int q = 0; q < RDIM; q++) {
        g1  = __builtin_fmaf(sk, wg[q], g1);
        dot = __builtin_fmaf(sk, ws[q], dot);
        float sn = __builtin_fmaf(c2, sk, -skm1);
        skm1 = sk; sk = sn;
      }
      float2 f01 = __half22float2(*(__half2*)&Y0.x);
      float2 fzg = __half22float2(*(__half2*)&Y0.y);
      acc0 = __builtin_fmaf(g1, f01.x, acc0);
      acc1 = __builtin_fmaf(g1, f01.y, acc1);
      accs += leaky(dot + fzg.x);
      c0 = c1; p0 = p1; c1 = cn; p1 = p2; Y0 = Y1; Y1 = Y2;
    }
  }
  float id = 1.0f / fmaxf((float)(bnd - a), 1.0f);
  uint2 Yg = yzg[(n << 4) + r];
  float gt = __half22float2(*(__half2*)&Yg.y).y;
  float2* xr2 = (float2*)xr;
  float2 x = xr2[(n << 4) + r];
  x.x += acc0 * id * gt;
  x.y += acc1 * id * gt;
  xr2[(n << 4) + r] = x;                // in-place safe: (n,r) written only by this thread
  float s_new = xs[(n << 4) + r] + accs * id;
  xs[(n << 4) + r] = s_new;

  if (write_next) {
    // fused k_pre for next layer: cross-r via 16-wide shuffles (same sum order as k_pre)
    float wmxn[16], wsan[16], wgtn[16];
#pragma unroll
    for (int q = 0; q < 16; q++) wmxn[q] = Wmixn[r * 16 + q];
#pragma unroll
    for (int q = 0; q < 16; q++) wsan[q] = Ws1n[q * 16 + r];
#pragma unroll
    for (int q = 0; q < 16; q++) wgtn[q] = Wgaten[q * 16 + r];
    float y0 = 0.f, y1 = 0.f;
    float z = bs1n[r], gtn = bgaten[r];
#pragma unroll
    for (int j = 0; j < 16; j++) {
      float xj0 = __shfl(x.x, j, 16);
      float xj1 = __shfl(x.y, j, 16);
      float sj  = __shfl(s_new, j, 16);
      y0 += wmxn[j] * xj0;
      y1 += wmxn[j] * xj1;
      z  += wsan[j] * sj;
      gtn += wgtn[j] * sj;
    }
    gtn = 1.0f / (1.0f + __expf(-gtn));
    __half2 hA = __floats2half2_rn(y0, y1);
    __half2 hB = __floats2half2_rn(z, gtn);
    uint2 w2;
    w2.x = *(unsigned int*)&hA;
    w2.y = *(unsigned int*)&hB;
    yzg_out[(n << 4) + r] = w2;
  }
}

// ---------- final rotate-out + MLP (wave-uniform scalar weight loads) + binned graph sum ----------
__global__ void __launch_bounds__(128) k_final(
    int N, const float* __restrict__ xr, const float* __restrict__ xs,
    const float* __restrict__ cthn, const float* __restrict__ sthn,
    const int* __restrict__ batch,
    const float* __restrict__ W1, const float* __restrict__ b1,
    const float* __restrict__ W2, const float* __restrict__ b2,
    float* __restrict__ out) {
  __shared__ float obin[320 * 6];
  int t = threadIdx.x;
  int start = blockIdx.x * 128;
  int n = start + t;
  int b0 = batch[min(start, N - 1)];
  int span = batch[min(start + 127, N - 1)] - b0;
  bool useLds = (span < 320);
  if (useLds) for (int i = t; i < (span + 1) * 6; i += 128) obin[i] = 0.f;
  __syncthreads();

  float u[NC];
  bool act = (n < N);
  if (act) {
    float xc[48];
    const float4* xs4 = (const float4*)(xs + (size_t)n * NS);
#pragma unroll
    for (int j = 0; j < 4; j++) {
      float4 v = xs4[j];
      xc[4 * j + 0] = v.x; xc[4 * j + 1] = v.y; xc[4 * j + 2] = v.z; xc[4 * j + 3] = v.w;
    }
    float c = cthn[n], s = sthn[n];
    const float4* xr4 = (const float4*)(xr + (size_t)n * 32);
#pragma unroll
    for (int j = 0; j < 8; j++) {
      float4 v = xr4[j];
      xc[16 + 4 * j + 0] = c * v.x - s * v.y;
      xc[16 + 4 * j + 1] = s * v.x + c * v.y;
      xc[16 + 4 * j + 2] = c * v.z - s * v.w;
      xc[16 + 4 * j + 3] = s * v.z + c * v.w;
    }
#pragma unroll
    for (int q = 0; q < NC; q++) u[q] = b2[q];
    for (int h = 0; h < H1; h += 4) {
      float a0 = b1[h + 0], a1 = b1[h + 1], a2 = b1[h + 2], a3 = b1[h + 3];
#pragma unroll
      for (int q = 0; q < 48; q++) {
        // uniform address (h,q uniform) -> s_load_dwordx4, cached in K$/L1
        float4 w = *(const float4*)(W1 + (size_t)q * H1 + h);
        float x = xc[q];
        a0 = __builtin_fmaf(x, w.x, a0);
        a1 = __builtin_fmaf(x, w.y, a1);
        a2 = __builtin_fmaf(x, w.z, a2);
        a3 = __builtin_fmaf(x, w.w, a3);
      }
      a0 = leaky(a0); a1 = leaky(a1); a2 = leaky(a2); a3 = leaky(a3);
#pragma unroll
      for (int q = 0; q < NC; q++)
        u[q] += a0 * W2[(h + 0) * 6 + q] + a1 * W2[(h + 1) * 6 + q]
              + a2 * W2[(h + 2) * 6 + q] + a3 * W2[(h + 3) * 6 + q];
    }
  }
  if (useLds) {
    if (act) {
      int rb = batch[n] - b0;
#pragma unroll
      for (int q = 0; q < NC; q++) atomicAdd(&obin[rb * 6 + q], u[q]);
    }
    __syncthreads();
    for (int i = t; i < (span + 1) * 6; i += 128) atomicAdd(&out[b0 * 6 + i], obin[i]);
  } else if (act) {
    int b = batch[n];
#pragma unroll
    for (int q = 0; q < NC; q++) atomicAdd(&out[b * 6 + q], u[q]);
  }
}

extern "C" void kernel_launch(void* const* d_in, const int* in_sizes, int n_in,
                              void* d_out, int out_size, void* d_ws, size_t ws_size,
                              hipStream_t stream) {
  const float* pos   = (const float*)d_in[0];
  const float* Wer   = (const float*)d_in[1];
  const float* wse   = (const float*)d_in[2];
  const float* bse   = (const float*)d_in[3];
  const float* Wg    = (const float*)d_in[4];
  const float* bg    = (const float*)d_in[5];
  const float* Wmix  = (const float*)d_in[6];
  const float* Wgate = (const float*)d_in[7];
  const float* bgate = (const float*)d_in[8];
  const float* Ws1   = (const float*)d_in[9];
  const float* bs1   = (const float*)d_in[10];
  const float* W1    = (const float*)d_in[11];
  const float* b1    = (const float*)d_in[12];
  const float* W2    = (const float*)d_in[13];
  const float* b2    = (const float*)d_in[14];
  const int*   ei    = (const int*)d_in[15];
  const int*   batch = (const int*)d_in[16];
  float* out = (float*)d_out;

  int N = in_sizes[0] / 2;
  int E = in_sizes[15] / 2;
  int G = out_size / NC;

  // ---- workspace layout (~55 MB for N=100k, E=1.6M) ----
  float* W = (float*)d_ws;
  size_t o = 0;
  float* gsum   = W + o; o += (size_t)2 * G;
  float* gcnt   = W + o; o += (size_t)G;
  int*   cnt    = (int*)(W + o); o += (size_t)N;
  int*   cursor = (int*)(W + o); o += (size_t)N;
  int*   dhist  = (int*)(W + o); o += (size_t)DBINS;
  size_t zero_bytes = o * 4;
  o = (o + 3) & ~(size_t)3;
  float* posc   = W + o; o += (size_t)2 * N;
  float* cthn   = W + o; o += (size_t)N;
  float* sthn   = W + o; o += (size_t)N;
  int*   off    = (int*)(W + o); o += (size_t)N + 1; o = (o + 3) & ~(size_t)3;
  int*   bsum   = (int*)(W + o); o += (size_t)1024;
  int*   dcur   = (int*)(W + o); o += (size_t)DBINS;
  int*   perm   = (int*)(W + o); o += (size_t)N; o = (o + 3) & ~(size_t)3;
  int*   adj    = (int*)(W + o); o += (size_t)E; o = (o + 1) & ~(size_t)1;
  float2* spc   = (float2*)(W + o); o += (size_t)2 * E;
  uint2* yzgA   = (uint2*)(W + o); o += (size_t)32 * N;
  uint2* yzgB   = (uint2*)(W + o); o += (size_t)32 * N;
  float* xr     = W + o; o += (size_t)N * 32;
  float* xs     = W + o; o += (size_t)N * 16;
  (void)ws_size;

  hipMemsetAsync(d_ws, 0, zero_bytes, stream);
  hipMemsetAsync(d_out, 0, (size_t)out_size * 4, stream);

  int nbN  = (N + 255) / 256;
  int nbE  = (E + 255) / 256;
  int nbE8 = NXCD * ((E + 255) / 256);
  int nbN16 = ((size_t)N * 16 + 255) / 256;
  int nbS  = (N + 1023) / 1024;
  int nbS3 = (N + 1 + 1023) / 1024;
  int nbF  = (N + 127) / 128;

  k_gsum_count<<<nbE8, 256, 0, stream>>>(pos, batch, N, gsum, gcnt, ei, E, cnt);
  k_center_dhist_scan1<<<nbS, 1024, 0, stream>>>(pos, batch, N, gsum, gcnt,
                                                 posc, cthn, sthn, cnt, dhist, off, bsum);
  k_dscan_scan2<<<1, 1024, 0, stream>>>(dhist, dcur, bsum, nbS);
  k_dfill_scan3<<<nbS3, 1024, 0, stream>>>(off, bsum, N, E, cnt, dcur, perm, cursor);
  k_scatter8<<<nbE8, 256, 0, stream>>>(ei, E, N, cursor, adj);
  k_init16<<<nbN16, 256, 0, stream>>>(N, off, adj, posc, spc, Wer, wse, bse,
                                      Wmix, Ws1, bs1, Wgate, bgate,
                                      xr, xs, yzgA);

  // layer 0: read A, write B (fused pre for layer 1)
  k_layer<<<nbN16, 256, 0, stream>>>(N, off, adj, spc, yzgA, perm,
                                     Wg, bg, Ws1, xr, xs,
                                     1, yzgB,
                                     Wmix + 256, Ws1 + 512, bs1 + 16, Wgate + 256, bgate + 16);
  // layer 1: read B, write A (fused pre for layer 2)
  k_layer<<<nbN16, 256, 0, stream>>>(N, off, adj, spc, yzgB, perm,
                                     Wg + 256, bg + 16, Ws1 + 512, xr, xs,
                                     1, yzgA,
                                     Wmix + 512, Ws1 + 1024, bs1 + 32, Wgate + 512, bgate + 32);
  // layer 2: read A, no next
  k_layer<<<nbN16, 256, 0, stream>>>(N, off, adj, spc, yzgA, perm,
                                     Wg + 512, bg + 32, Ws1 + 1024, xr, xs,
                                     0, yzgB,
                                     Wmix, Ws1, bs1, Wgate, bgate);

  k_final<<<nbF, 128, 0, stream>>>(N, xr, xs, cthn, sthn, batch, W1, b1, W2, b2, out);
}

// Round 7
// 490.969 us; speedup vs baseline: 1.2838x; 1.0847x over previous
//
#include <hip/hip_runtime.h>
#include <hip/hip_fp16.h>
#include <math.h>

#define NREP 16
#define RDIM 16
#define NS   16
#define NC   6
#define H1   144
#define DBINS 64
#define TILE 4096
#define P2CAP 10240   // pass-2 LDS adj capacity (40KB); mean bucket = 4096 edges

static __device__ __forceinline__ float leaky(float v) { return v > 0.0f ? v : 0.01f * v; }

// ---------- fused: per-graph mean (LDS-binned) + edge row count (round-3 form) ----------
__global__ void k_gsum_count(const float* __restrict__ pos, const int* __restrict__ batch,
                             int N, float* __restrict__ gsum, float* __restrict__ gcnt,
                             const int* __restrict__ ei, int E, int* __restrict__ cnt) {
  int t = threadIdx.x;
  int e = blockIdx.x * 256 + t;
  if (e < E) atomicAdd(&cnt[ei[e]], 1);

  __shared__ float bx[320], by[320], bc[320];
  int start = blockIdx.x * 256;
  if (start >= N) return;
  int n = start + t;
  int b0 = batch[min(start, N - 1)];
  int span = batch[min(start + 255, N - 1)] - b0;
  bool useLds = (span < 320);
  if (useLds) {
    for (int i = t; i <= span; i += 256) { bx[i] = 0.f; by[i] = 0.f; bc[i] = 0.f; }
    __syncthreads();
    if (n < N) {
      int rb = batch[n] - b0;
      atomicAdd(&bx[rb], pos[2 * n + 0]);
      atomicAdd(&by[rb], pos[2 * n + 1]);
      atomicAdd(&bc[rb], 1.0f);
    }
    __syncthreads();
    for (int i = t; i <= span; i += 256) {
      if (bc[i] != 0.0f) {
        atomicAdd(&gsum[2 * (b0 + i) + 0], bx[i]);
        atomicAdd(&gsum[2 * (b0 + i) + 1], by[i]);
        atomicAdd(&gcnt[b0 + i], bc[i]);
      }
    }
  } else if (n < N) {
    int b = batch[n];
    atomicAdd(&gsum[2 * b + 0], pos[2 * n + 0]);
    atomicAdd(&gsum[2 * b + 1], pos[2 * n + 1]);
    atomicAdd(&gcnt[b], 1.0f);
  }
}

// ---------- fused: center + degree histogram + scan phase 1 ----------
__global__ void k_center_dhist_scan1(
    const float* __restrict__ pos, const int* __restrict__ batch, int N,
    const float* __restrict__ gsum, const float* __restrict__ gcnt,
    float* __restrict__ posc, float* __restrict__ cthn, float* __restrict__ sthn,
    const int* __restrict__ cnt, int* __restrict__ dhist,
    int* __restrict__ off, int* __restrict__ bsum) {
  __shared__ int lh[DBINS];
  __shared__ int sd[1024];
  int t = threadIdx.x;
  int i = blockIdx.x * 1024 + t;
  if (t < DBINS) lh[t] = 0;
  int v = (i < N) ? cnt[i] : 0;
  sd[t] = v;
  if (i < N) {
    int b = batch[i];
    float invc = 1.0f / fmaxf(gcnt[b], 1.0f);
    float px = pos[2 * i + 0] - gsum[2 * b + 0] * invc;
    float py = pos[2 * i + 1] - gsum[2 * b + 1] * invc;
    posc[2 * i + 0] = px;
    posc[2 * i + 1] = py;
    float r = sqrtf(px * px + py * py);
    if (r > 0.0f) { cthn[i] = px / r; sthn[i] = py / r; }
    else          { cthn[i] = 1.0f;  sthn[i] = 0.0f; }
  }
  __syncthreads();
  if (i < N) atomicAdd(&lh[min(v, DBINS - 1)], 1);
  for (int o = 1; o < 1024; o <<= 1) {
    int u = (t >= o) ? sd[t - o] : 0;
    __syncthreads();
    sd[t] += u;
    __syncthreads();
  }
  if (i < N) off[i] = sd[t] - v;
  if (t == 1023) bsum[blockIdx.x] = sd[1023];
  if (t < DBINS && lh[t] > 0) atomicAdd(&dhist[t], lh[t]);
}

// ---------- fused: degree-bin exclusive scan + block-sum exclusive scan ----------
__global__ void k_dscan_scan2(const int* __restrict__ dhist, int* __restrict__ dcur,
                              int* __restrict__ bsum, int nb) {
  __shared__ int s1[DBINS];
  __shared__ int s2[1024];
  int t = threadIdx.x;
  int v1 = (t < DBINS) ? dhist[t] : 0;
  if (t < DBINS) s1[t] = v1;
  int v2 = (t < nb) ? bsum[t] : 0;
  s2[t] = v2;
  __syncthreads();
  for (int o = 1; o < 1024; o <<= 1) {
    int u1 = (o < DBINS && t >= o && t < DBINS) ? s1[t - o] : 0;
    int u2 = (t >= o) ? s2[t - o] : 0;
    __syncthreads();
    if (o < DBINS && t < DBINS) s1[t] += u1;
    s2[t] += u2;
    __syncthreads();
  }
  if (t < DBINS) dcur[t] = s1[t] - v1;
  if (t < nb) bsum[t] = s2[t] - v2;
}

// ---------- fused: scan phase 3 + degree-sort fill + cursor/bcur init ----------
__global__ void k_dfill_scan3(int* __restrict__ off, const int* __restrict__ bsum,
                              int N, int E,
                              const int* __restrict__ cnt, int* __restrict__ dcur,
                              int* __restrict__ perm, int* __restrict__ cursor,
                              int* __restrict__ bcur) {
  int t = threadIdx.x;
  int i = blockIdx.x * 1024 + t;
  if (i < N) {
    int ov = off[i] + bsum[blockIdx.x];
    off[i] = ov;
    cursor[i] = ov;                     // fallback scatter slots start at off[i]
    if ((i & 255) == 0) bcur[i >> 8] = ov;   // bucket b's ebuf region starts at off[b<<8]
  }
  if (i == N) off[N] = E;

  __shared__ int lh[DBINS];
  __shared__ int base[DBINS];
  if (t < DBINS) lh[t] = 0;
  __syncthreads();
  int b = 0, lr = 0;
  if (i < N) {
    b = min(cnt[i], DBINS - 1);
    lr = atomicAdd(&lh[b], 1);
  }
  __syncthreads();
  if (t < DBINS && lh[t] > 0) base[t] = atomicAdd(&dcur[t], lh[t]);
  __syncthreads();
  if (i < N) perm[base[b] + lr] = i;
}

// ---------- CSR build pass 1: bucket-partition edges by row>>8 ----------
// Random global scatter can't write-combine (r2/r3/r4: ~1 line-writeback per 4B store,
// regardless of XCD partition or nt policy — a line's ~16 stores span the whole kernel).
// Fix: do the random permutation in LDS. Pass 1 groups edges by 256-row bucket: LDS
// histogram -> block scan -> one global atomicAdd per (bucket,block) reserves a contiguous
// run in ebuf's bucket region ([off[b<<8], off[(b+1)<<8]) by CSR construction) -> staged
// copy-out in ~10-edge coalesced runs. ebuf ALIASES spc (disjoint liveness; keeps the
// workspace at the proven ~67MB footprint — r6 container failures may have been ws overflow).
__global__ void __launch_bounds__(256) k_part1(
    const int* __restrict__ ei, int E,
    int* __restrict__ bcur, long long* __restrict__ ebuf) {
  __shared__ int hist[512], lofs[512], gbase[512], pc[512];
  __shared__ long long stg[TILE];
  __shared__ unsigned short bkt[TILE];
  int t = threadIdx.x;
  int base = blockIdx.x * TILE;
  int cntt = min(TILE, E - base);
  for (int i = t; i < 512; i += 256) { hist[i] = 0; pc[i] = 0; }
  __syncthreads();
  int r[16], c[16];
#pragma unroll
  for (int i = 0; i < 16; i++) {
    int e = base + t + i * 256;
    r[i] = -1;
    if (e < E) {
      r[i] = ei[e];
      c[i] = ei[E + e];
      atomicAdd(&hist[r[i] >> 8], 1);
    }
  }
  __syncthreads();
  // inclusive scan of hist over 512 entries (2 per thread), then make exclusive
  lofs[t] = hist[t]; lofs[t + 256] = hist[t + 256];
  __syncthreads();
  for (int o = 1; o < 512; o <<= 1) {
    int a0 = (t >= o) ? lofs[t - o] : 0;
    int a1 = lofs[t + 256 - o];
    __syncthreads();
    lofs[t] += a0; lofs[t + 256] += a1;
    __syncthreads();
  }
  int e0 = lofs[t] - hist[t], e1 = lofs[t + 256] - hist[t + 256];
  __syncthreads();
  lofs[t] = e0; lofs[t + 256] = e1;
  __syncthreads();
  for (int i = t; i < 512; i += 256)
    if (hist[i] > 0) gbase[i] = atomicAdd(&bcur[i], hist[i]);
  __syncthreads();
#pragma unroll
  for (int i = 0; i < 16; i++) {
    if (r[i] >= 0) {
      int b = r[i] >> 8;
      int l = lofs[b] + atomicAdd(&pc[b], 1);
      stg[l] = ((long long)r[i] << 32) | (unsigned int)c[i];
      bkt[l] = (unsigned short)b;
    }
  }
  __syncthreads();
  for (int j = t; j < cntt; j += 256) {
    int b = bkt[j];
    ebuf[gbase[b] + (j - lofs[b])] = stg[j];
  }
}

// ---------- CSR build pass 2: in-LDS row scatter per bucket + coalesced adj write ----------
__global__ void __launch_bounds__(256) k_part2(
    const int* __restrict__ off, int N, const long long* __restrict__ ebuf,
    int* __restrict__ cursor, int* __restrict__ adj) {
  __shared__ int lcur[256];
  __shared__ int ladj[P2CAP];
  int t = threadIdx.x;
  int r0 = blockIdx.x << 8;
  int rend = min(r0 + 256, N);
  int abeg = off[r0];
  int aend = off[rend];
  int sz = aend - abeg;
  lcur[t] = (r0 + t < N) ? (off[r0 + t] - abeg) : 0;
  __syncthreads();
  if (sz <= P2CAP) {
    for (int j = abeg + t; j < aend; j += 256) {
      long long p = ebuf[j];
      int cl = (int)(unsigned int)(p & 0xffffffffLL);
      int rr = (int)(p >> 32);
      int l = atomicAdd(&lcur[rr - r0], 1);
      ladj[l] = cl;
    }
    __syncthreads();
    for (int j = t; j < sz; j += 256) adj[abeg + j] = ladj[j];
  } else {
    // degenerate bucket (>10240 edges): fall back to global cursor scatter
    for (int j = abeg + t; j < aend; j += 256) {
      long long p = ebuf[j];
      int cl = (int)(unsigned int)(p & 0xffffffffLL);
      int rr = (int)(p >> 32);
      int l = atomicAdd(&cursor[rr], 1);
      adj[l] = cl;
    }
  }
}

// ---------- fused node init + per-edge trig fill + layer-0 pre ----------
// NOTE: reads adj (written by k_part2) and writes spc, which ALIASES ebuf — ebuf is dead
// by this point (consumed entirely by k_part2).
__global__ void __launch_bounds__(256) k_init16(
    int N, const int* __restrict__ off, const int* __restrict__ adj,
    const float* __restrict__ posc, float2* __restrict__ spc,
    const float* __restrict__ Wer, const float* __restrict__ wse, const float* __restrict__ bse,
    const float* __restrict__ Wmix, const float* __restrict__ Ws1, const float* __restrict__ bs1,
    const float* __restrict__ Wgate, const float* __restrict__ bgate,
    float* __restrict__ xr, float* __restrict__ xs, uint2* __restrict__ yzg) {
  int idx = blockIdx.x * 256 + threadIdx.x;
  int n = idx >> 4, r = idx & 15;
  if (n >= N) return;
  int a = off[n], b = off[n + 1];
  float px = posc[2 * n + 0], py = posc[2 * n + 1];
  float C = 0.f, S = 0.f, D = 0.f;
  for (int k = a + r; k < b; k += 16) {
    int cl = adj[k];
    float dx = px - posc[2 * cl + 0];
    float dy = py - posc[2 * cl + 1];
    float d = sqrtf(dx * dx + dy * dy);
    float sp, cp;
    sincospif(d, &sp, &cp);
    float spp = 1.41421356237309515f * sp / (d + 1e-8f);
    spc[k] = make_float2(spp, 2.0f * cp);
    if (d > 0.0f) {
      float inv = 1.0f / d;
      C += dx * inv;
      S += dy * inv;
    } else {
      C += 1.0f;
    }
    D += d;
  }
#pragma unroll
  for (int o = 1; o < 16; o <<= 1) {         // butterfly: all 16 lanes get full sums
    C += __shfl_xor(C, o, 16);
    S += __shfl_xor(S, o, 16);
    D += __shfl_xor(D, o, 16);
  }
  float id = 1.0f / fmaxf((float)(b - a), 1.0f);
  C *= id; S *= id;
  float dm = D * id;
  float w0 = Wer[2 * r], w1 = Wer[2 * r + 1];
  float2 x;
  x.x = C * w0 - S * w1;
  x.y = S * w0 + C * w1;
  ((float2*)xr)[(size_t)n * 16 + r] = x;
  float s_new = leaky(dm * wse[r] + bse[r]);
  xs[(size_t)n * 16 + r] = s_new;

  float wmxn[16], wsan[16], wgtn[16];
#pragma unroll
  for (int q = 0; q < 16; q++) wmxn[q] = Wmix[r * 16 + q];
#pragma unroll
  for (int q = 0; q < 16; q++) wsan[q] = Ws1[q * 16 + r];
#pragma unroll
  for (int q = 0; q < 16; q++) wgtn[q] = Wgate[q * 16 + r];
  float y0 = 0.f, y1 = 0.f;
  float z = bs1[r], gtn = bgate[r];
#pragma unroll
  for (int j = 0; j < 16; j++) {
    float xj0 = __shfl(x.x, j, 16);
    float xj1 = __shfl(x.y, j, 16);
    float sj  = __shfl(s_new, j, 16);
    y0 += wmxn[j] * xj0;
    y1 += wmxn[j] * xj1;
    z  += wsan[j] * sj;
    gtn += wgtn[j] * sj;
  }
  gtn = 1.0f / (1.0f + __expf(-gtn));
  __half2 hA = __floats2half2_rn(y0, y1);
  __half2 hB = __floats2half2_rn(z, gtn);
  uint2 w2;
  w2.x = *(unsigned int*)&hA;
  w2.y = *(unsigned int*)&hB;
  yzg[(size_t)n * 16 + r] = w2;
}

// ---------- EqBlock layer + fused next-layer pre (peeled prefetch, SoA adj+spc) ----------
__global__ void __launch_bounds__(256) k_layer(
    int N, const int* __restrict__ off,
    const int* __restrict__ adj, const float2* __restrict__ spc,
    const uint2* __restrict__ yzg, const int* __restrict__ perm,
    const float* __restrict__ Wg, const float* __restrict__ bg,
    const float* __restrict__ Ws1,   // this layer; demb rows are 16..31
    float* xr, float* xs,
    int write_next, uint2* __restrict__ yzg_out,
    const float* __restrict__ Wmixn, const float* __restrict__ Ws1n,
    const float* __restrict__ bs1n,
    const float* __restrict__ Wgaten, const float* __restrict__ bgaten) {
  int idx = blockIdx.x * 256 + threadIdx.x;
  int g = idx >> 4, r = idx & 15;
  if (g >= N) return;
  int n = perm[g];                      // degree-sorted: waves get equal-degree nodes
  float wg[16], ws[16];
#pragma unroll
  for (int q = 0; q < 16; q++) wg[q] = Wg[q * 16 + r];
#pragma unroll
  for (int q = 0; q < 16; q++) ws[q] = Ws1[(16 + q) * 16 + r];
  float bgr = bg[r];

  int a = off[n], bnd = off[n + 1];
  float acc0 = 0.f, acc1 = 0.f, accs = 0.f;
  if (a < bnd) {
    int last = bnd - 1;
    int    c0 = adj[a];               float2 p0 = spc[a];
    int    c1 = adj[min(a + 1, last)]; float2 p1 = spc[min(a + 1, last)];
    int    cn = adj[min(a + 2, last)]; float2 p2 = spc[min(a + 2, last)];
    uint2 Y0 = yzg[(c0 << 4) + r];
    uint2 Y1 = yzg[(c1 << 4) + r];
    int k = a;
    for (; k + 3 < bnd; k++) {
      int c3 = adj[k + 3];
      float2 p3 = spc[k + 3];
      uint2 Y2 = yzg[(cn << 4) + r];
      float skm1 = 0.f, sk = p0.x, c2 = p0.y;
      float g1 = bgr, dot = 0.f;
#pragma unroll
      for (int q = 0; q < RDIM; q++) {
        g1  = __builtin_fmaf(sk, wg[q], g1);
        dot = __builtin_fmaf(sk, ws[q], dot);
        float sn = __builtin_fmaf(c2, sk, -skm1);
        skm1 = sk; sk = sn;
      }
      float2 f01 = __half22float2(*(__half2*)&Y0.x);
      float2 fzg = __half22float2(*(__half2*)&Y0.y);
      acc0 = __builtin_fmaf(g1, f01.x, acc0);
      acc1 = __builtin_fmaf(g1, f01.y, acc1);
      accs += leaky(dot + fzg.x);
      c0 = c1; p0 = p1; c1 = cn; p1 = p2; cn = c3; p2 = p3; Y0 = Y1; Y1 = Y2;
    }
    for (; k < bnd; k++) {
      uint2 Y2 = Y1;
      if (k + 2 < bnd) Y2 = yzg[(cn << 4) + r];
      float skm1 = 0.f, sk = p0.x, c2 = p0.y;
      float g1 = bgr, dot = 0.f;
#pragma unroll
      for (int q = 0; q < RDIM; q++) {
        g1  = __builtin_fmaf(sk, wg[q], g1);
        dot = __builtin_fmaf(sk, ws[q], dot);
        float sn = __builtin_fmaf(c2, sk, -skm1);
        skm1 = sk; sk = sn;
      }
      float2 f01 = __half22float2(*(__half2*)&Y0.x);
      float2 fzg = __half22float2(*(__half2*)&Y0.y);
      acc0 = __builtin_fmaf(g1, f01.x, acc0);
      acc1 = __builtin_fmaf(g1, f01.y, acc1);
      accs += leaky(dot + fzg.x);
      c0 = c1; p0 = p1; c1 = cn; p1 = p2; Y0 = Y1; Y1 = Y2;
    }
  }
  float id = 1.0f / fmaxf((float)(bnd - a), 1.0f);
  uint2 Yg = yzg[(n << 4) + r];
  float gt = __half22float2(*(__half2*)&Yg.y).y;
  float2* xr2 = (float2*)xr;
  float2 x = xr2[(n << 4) + r];
  x.x += acc0 * id * gt;
  x.y += acc1 * id * gt;
  xr2[(n << 4) + r] = x;                // in-place safe: (n,r) written only by this thread
  float s_new = xs[(n << 4) + r] + accs * id;
  xs[(n << 4) + r] = s_new;

  if (write_next) {
    float wmxn[16], wsan[16], wgtn[16];
#pragma unroll
    for (int q = 0; q < 16; q++) wmxn[q] = Wmixn[r * 16 + q];
#pragma unroll
    for (int q = 0; q < 16; q++) wsan[q] = Ws1n[q * 16 + r];
#pragma unroll
    for (int q = 0; q < 16; q++) wgtn[q] = Wgaten[q * 16 + r];
    float y0 = 0.f, y1 = 0.f;
    float z = bs1n[r], gtn = bgaten[r];
#pragma unroll
    for (int j = 0; j < 16; j++) {
      float xj0 = __shfl(x.x, j, 16);
      float xj1 = __shfl(x.y, j, 16);
      float sj  = __shfl(s_new, j, 16);
      y0 += wmxn[j] * xj0;
      y1 += wmxn[j] * xj1;
      z  += wsan[j] * sj;
      gtn += wgtn[j] * sj;
    }
    gtn = 1.0f / (1.0f + __expf(-gtn));
    __half2 hA = __floats2half2_rn(y0, y1);
    __half2 hB = __floats2half2_rn(z, gtn);
    uint2 w2;
    w2.x = *(unsigned int*)&hA;
    w2.y = *(unsigned int*)&hB;
    yzg_out[(n << 4) + r] = w2;
  }
}

// ---------- final rotate-out + MLP (wave-uniform scalar weight loads) + binned graph sum ----------
__global__ void __launch_bounds__(128) k_final(
    int N, const float* __restrict__ xr, const float* __restrict__ xs,
    const float* __restrict__ cthn, const float* __restrict__ sthn,
    const int* __restrict__ batch,
    const float* __restrict__ W1, const float* __restrict__ b1,
    const float* __restrict__ W2, const float* __restrict__ b2,
    float* __restrict__ out) {
  __shared__ float obin[320 * 6];
  int t = threadIdx.x;
  int start = blockIdx.x * 128;
  int n = start + t;
  int b0 = batch[min(start, N - 1)];
  int span = batch[min(start + 127, N - 1)] - b0;
  bool useLds = (span < 320);
  if (useLds) for (int i = t; i < (span + 1) * 6; i += 128) obin[i] = 0.f;
  __syncthreads();

  float u[NC];
  bool act = (n < N);
  if (act) {
    float xc[48];
    const float4* xs4 = (const float4*)(xs + (size_t)n * NS);
#pragma unroll
    for (int j = 0; j < 4; j++) {
      float4 v = xs4[j];
      xc[4 * j + 0] = v.x; xc[4 * j + 1] = v.y; xc[4 * j + 2] = v.z; xc[4 * j + 3] = v.w;
    }
    float c = cthn[n], s = sthn[n];
    const float4* xr4 = (const float4*)(xr + (size_t)n * 32);
#pragma unroll
    for (int j = 0; j < 8; j++) {
      float4 v = xr4[j];
      xc[16 + 4 * j + 0] = c * v.x - s * v.y;
      xc[16 + 4 * j + 1] = s * v.x + c * v.y;
      xc[16 + 4 * j + 2] = c * v.z - s * v.w;
      xc[16 + 4 * j + 3] = s * v.z + c * v.w;
    }
#pragma unroll
    for (int q = 0; q < NC; q++) u[q] = b2[q];
    for (int h = 0; h < H1; h += 4) {
      float a0 = b1[h + 0], a1 = b1[h + 1], a2 = b1[h + 2], a3 = b1[h + 3];
#pragma unroll
      for (int q = 0; q < 48; q++) {
        float4 w = *(const float4*)(W1 + (size_t)q * H1 + h);
        float x = xc[q];
        a0 = __builtin_fmaf(x, w.x, a0);
        a1 = __builtin_fmaf(x, w.y, a1);
        a2 = __builtin_fmaf(x, w.z, a2);
        a3 = __builtin_fmaf(x, w.w, a3);
      }
      a0 = leaky(a0); a1 = leaky(a1); a2 = leaky(a2); a3 = leaky(a3);
#pragma unroll
      for (int q = 0; q < NC; q++)
        u[q] += a0 * W2[(h + 0) * 6 + q] + a1 * W2[(h + 1) * 6 + q]
              + a2 * W2[(h + 2) * 6 + q] + a3 * W2[(h + 3) * 6 + q];
    }
  }
  if (useLds) {
    if (act) {
      int rb = batch[n] - b0;
#pragma unroll
      for (int q = 0; q < NC; q++) atomicAdd(&obin[rb * 6 + q], u[q]);
    }
    __syncthreads();
    for (int i = t; i < (span + 1) * 6; i += 128) atomicAdd(&out[b0 * 6 + i], obin[i]);
  } else if (act) {
    int b = batch[n];
#pragma unroll
    for (int q = 0; q < NC; q++) atomicAdd(&out[b * 6 + q], u[q]);
  }
}

extern "C" void kernel_launch(void* const* d_in, const int* in_sizes, int n_in,
                              void* d_out, int out_size, void* d_ws, size_t ws_size,
                              hipStream_t stream) {
  const float* pos   = (const float*)d_in[0];
  const float* Wer   = (const float*)d_in[1];
  const float* wse   = (const float*)d_in[2];
  const float* bse   = (const float*)d_in[3];
  const float* Wg    = (const float*)d_in[4];
  const float* bg    = (const float*)d_in[5];
  const float* Wmix  = (const float*)d_in[6];
  const float* Wgate = (const float*)d_in[7];
  const float* bgate = (const float*)d_in[8];
  const float* Ws1   = (const float*)d_in[9];
  const float* bs1   = (const float*)d_in[10];
  const float* W1    = (const float*)d_in[11];
  const float* b1    = (const float*)d_in[12];
  const float* W2    = (const float*)d_in[13];
  const float* b2    = (const float*)d_in[14];
  const int*   ei    = (const int*)d_in[15];
  const int*   batch = (const int*)d_in[16];
  float* out = (float*)d_out;

  int N = in_sizes[0] / 2;
  int E = in_sizes[15] / 2;
  int G = out_size / NC;

  // ---- workspace layout (~67 MB for N=100k, E=1.6M; ebuf aliases spc) ----
  float* W = (float*)d_ws;
  size_t o = 0;
  float* gsum   = W + o; o += (size_t)2 * G;
  float* gcnt   = W + o; o += (size_t)G;
  int*   cnt    = (int*)(W + o); o += (size_t)N;
  int*   cursor = (int*)(W + o); o += (size_t)N;
  int*   dhist  = (int*)(W + o); o += (size_t)DBINS;
  size_t zero_bytes = o * 4;
  o = (o + 3) & ~(size_t)3;
  float* posc   = W + o; o += (size_t)2 * N;
  float* cthn   = W + o; o += (size_t)N;
  float* sthn   = W + o; o += (size_t)N;
  int*   off    = (int*)(W + o); o += (size_t)N + 1; o = (o + 3) & ~(size_t)3;
  int*   bsum   = (int*)(W + o); o += (size_t)1024;
  int*   dcur   = (int*)(W + o); o += (size_t)DBINS;
  int*   bcur   = (int*)(W + o); o += (size_t)512;
  int*   perm   = (int*)(W + o); o += (size_t)N; o = (o + 3) & ~(size_t)3;
  int*   adj    = (int*)(W + o); o += (size_t)E; o = (o + 1) & ~(size_t)1;
  float2* spc   = (float2*)(W + o); o += (size_t)2 * E;
  long long* ebuf = (long long*)spc;   // ALIAS: ebuf live in k_part1/k_part2 only; spc written after
  uint2* yzgA   = (uint2*)(W + o); o += (size_t)32 * N;
  uint2* yzgB   = (uint2*)(W + o); o += (size_t)32 * N;
  float* xr     = W + o; o += (size_t)N * 32;
  float* xs     = W + o; o += (size_t)N * 16;
  (void)ws_size;

  hipMemsetAsync(d_ws, 0, zero_bytes, stream);
  hipMemsetAsync(d_out, 0, (size_t)out_size * 4, stream);

  int nbE  = (E + 255) / 256;
  int nbN16 = ((size_t)N * 16 + 255) / 256;
  int nbS  = (N + 1023) / 1024;
  int nbS3 = (N + 1 + 1023) / 1024;
  int nbF  = (N + 127) / 128;
  int nbP1 = (E + TILE - 1) / TILE;
  int nbP2 = (N + 255) / 256;   // buckets of 256 rows

  k_gsum_count<<<nbE, 256, 0, stream>>>(pos, batch, N, gsum, gcnt, ei, E, cnt);
  k_center_dhist_scan1<<<nbS, 1024, 0, stream>>>(pos, batch, N, gsum, gcnt,
                                                 posc, cthn, sthn, cnt, dhist, off, bsum);
  k_dscan_scan2<<<1, 1024, 0, stream>>>(dhist, dcur, bsum, nbS);
  k_dfill_scan3<<<nbS3, 1024, 0, stream>>>(off, bsum, N, E, cnt, dcur, perm, cursor, bcur);
  k_part1<<<nbP1, 256, 0, stream>>>(ei, E, bcur, ebuf);
  k_part2<<<nbP2, 256, 0, stream>>>(off, N, ebuf, cursor, adj);
  k_init16<<<nbN16, 256, 0, stream>>>(N, off, adj, posc, spc, Wer, wse, bse,
                                      Wmix, Ws1, bs1, Wgate, bgate,
                                      xr, xs, yzgA);

  // layer 0: read A, write B (fused pre for layer 1)
  k_layer<<<nbN16, 256, 0, stream>>>(N, off, adj, spc, yzgA, perm,
                                     Wg, bg, Ws1, xr, xs,
                                     1, yzgB,
                                     Wmix + 256, Ws1 + 512, bs1 + 16, Wgate + 256, bgate + 16);
  // layer 1: read B, write A (fused pre for layer 2)
  k_layer<<<nbN16, 256, 0, stream>>>(N, off, adj, spc, yzgB, perm,
                                     Wg + 256, bg + 16, Ws1 + 512, xr, xs,
                                     1, yzgA,
                                     Wmix + 512, Ws1 + 1024, bs1 + 32, Wgate + 512, bgate + 32);
  // layer 2: read A, no next
  k_layer<<<nbN16, 256, 0, stream>>>(N, off, adj, spc, yzgA, perm,
                                     Wg + 512, bg + 32, Ws1 + 1024, xr, xs,
                                     0, yzgB,
                                     Wmix, Ws1, bs1, Wgate, bgate);

  k_final<<<nbF, 128, 0, stream>>>(N, xr, xs, cthn, sthn, batch, W1, b1, W2, b2, out);
}

// Round 8
// 446.224 us; speedup vs baseline: 1.4126x; 1.1003x over previous
//
#include <hip/hip_runtime.h>
#include <hip/hip_fp16.h>
#include <math.h>

#define NREP 16
#define RDIM 16
#define NS   16
#define NC   6
#define H1   144
#define DBINS 64
#define TILE 4096
#define NBMAX 512     // max 256-row buckets supported (N <= 131072)
#define P2CAP 10240   // bucket LDS adj capacity; mean bucket = 4096 edges

static __device__ __forceinline__ float leaky(float v) { return v > 0.0f ? v : 0.01f * v; }

// ---------- fused: per-graph mean (LDS-binned) + LDS-aggregated bucket histogram ----------
// Replaces the old E random atomicAdd(cnt[row]) (1.6M line-ping-pong atomics) with a
// 392-bin bucket histogram aggregated in LDS: 512 global atomics per 4096-edge tile.
__global__ void __launch_bounds__(256) k_gsum_bhist(
    const float* __restrict__ pos, const int* __restrict__ batch, int N,
    float* __restrict__ gsum, float* __restrict__ gcnt,
    const int* __restrict__ ei, int E, int* __restrict__ bhist) {
  int t = threadIdx.x;
  // E-part: bucket histogram over this block's 4096-edge tile
  __shared__ int h[NBMAX];
  for (int i = t; i < NBMAX; i += 256) h[i] = 0;
  __syncthreads();
  int base = blockIdx.x * TILE;
  int lim = min(base + TILE, E);
  for (int j = base + t; j < lim; j += 256) atomicAdd(&h[ei[j] >> 8], 1);
  __syncthreads();
  for (int i = t; i < NBMAX; i += 256)
    if (h[i] > 0) atomicAdd(&bhist[i], h[i]);

  // N-part: per-graph mean (unchanged LDS-binned form)
  __shared__ float bx[320], by[320], bc[320];
  int start = blockIdx.x * 256;
  if (start >= N) return;
  int n = start + t;
  int b0 = batch[min(start, N - 1)];
  int span = batch[min(start + 255, N - 1)] - b0;
  bool useLds = (span < 320);
  if (useLds) {
    for (int i = t; i <= span; i += 256) { bx[i] = 0.f; by[i] = 0.f; bc[i] = 0.f; }
    __syncthreads();
    if (n < N) {
      int rb = batch[n] - b0;
      atomicAdd(&bx[rb], pos[2 * n + 0]);
      atomicAdd(&by[rb], pos[2 * n + 1]);
      atomicAdd(&bc[rb], 1.0f);
    }
    __syncthreads();
    for (int i = t; i <= span; i += 256) {
      if (bc[i] != 0.0f) {
        atomicAdd(&gsum[2 * (b0 + i) + 0], bx[i]);
        atomicAdd(&gsum[2 * (b0 + i) + 1], by[i]);
        atomicAdd(&gcnt[b0 + i], bc[i]);
      }
    }
  } else if (n < N) {
    int b = batch[n];
    atomicAdd(&gsum[2 * b + 0], pos[2 * n + 0]);
    atomicAdd(&gsum[2 * b + 1], pos[2 * n + 1]);
    atomicAdd(&gcnt[b], 1.0f);
  }
}

// ---------- center (pure elementwise now) + block0: bucket-base scan ----------
__global__ void __launch_bounds__(256) k_center_bscan(
    const float* __restrict__ pos, const int* __restrict__ batch, int N, int E,
    const float* __restrict__ gsum, const float* __restrict__ gcnt,
    float* __restrict__ posc, float* __restrict__ cthn, float* __restrict__ sthn,
    const int* __restrict__ bhist, int* __restrict__ bbase, int* __restrict__ bcur, int NB) {
  int t = threadIdx.x;
  if (blockIdx.x == 0) {
    // exclusive scan of bhist[NB] (NB <= NBMAX=512): 256 threads x 2 elems
    __shared__ int s[NBMAX];
    int v0 = (t < NB) ? bhist[t] : 0;
    int v1 = (t + 256 < NB) ? bhist[t + 256] : 0;
    s[t] = v0; s[t + 256] = v1;
    __syncthreads();
    for (int o = 1; o < NBMAX; o <<= 1) {
      int a0 = (t >= o) ? s[t - o] : 0;
      int a1 = s[t + 256 - o];
      __syncthreads();
      s[t] += a0; s[t + 256] += a1;
      __syncthreads();
    }
    if (t < NB)       { int ex = s[t] - v0;       bbase[t] = ex;       bcur[t] = ex; }
    if (t + 256 < NB) { int ex = s[t + 256] - v1; bbase[t + 256] = ex; bcur[t + 256] = ex; }
    if (t == 0) bbase[NB] = E;
  }
  int i = blockIdx.x * 256 + t;
  if (i < N) {
    int b = batch[i];
    float invc = 1.0f / fmaxf(gcnt[b], 1.0f);
    float px = pos[2 * i + 0] - gsum[2 * b + 0] * invc;
    float py = pos[2 * i + 1] - gsum[2 * b + 1] * invc;
    posc[2 * i + 0] = px;
    posc[2 * i + 1] = py;
    float r = sqrtf(px * px + py * py);
    if (r > 0.0f) { cthn[i] = px / r; sthn[i] = py / r; }
    else          { cthn[i] = 1.0f;  sthn[i] = 0.0f; }
  }
}

// ---------- CSR build pass 1: bucket-partition edges by row>>8 (r7-proven form) ----------
__global__ void __launch_bounds__(256) k_part1(
    const int* __restrict__ ei, int E,
    int* __restrict__ bcur, long long* __restrict__ ebuf) {
  __shared__ int hist[NBMAX], lofs[NBMAX], gbase[NBMAX], pc[NBMAX];
  __shared__ long long stg[TILE];
  __shared__ unsigned short bkt[TILE];
  int t = threadIdx.x;
  int base = blockIdx.x * TILE;
  int cntt = min(TILE, E - base);
  for (int i = t; i < NBMAX; i += 256) { hist[i] = 0; pc[i] = 0; }
  __syncthreads();
  int r[16], c[16];
#pragma unroll
  for (int i = 0; i < 16; i++) {
    int e = base + t + i * 256;
    r[i] = -1;
    if (e < E) {
      r[i] = ei[e];
      c[i] = ei[E + e];
      atomicAdd(&hist[r[i] >> 8], 1);
    }
  }
  __syncthreads();
  lofs[t] = hist[t]; lofs[t + 256] = hist[t + 256];
  __syncthreads();
  for (int o = 1; o < NBMAX; o <<= 1) {
    int a0 = (t >= o) ? lofs[t - o] : 0;
    int a1 = lofs[t + 256 - o];
    __syncthreads();
    lofs[t] += a0; lofs[t + 256] += a1;
    __syncthreads();
  }
  int e0 = lofs[t] - hist[t], e1 = lofs[t + 256] - hist[t + 256];
  __syncthreads();
  lofs[t] = e0; lofs[t + 256] = e1;
  __syncthreads();
  for (int i = t; i < NBMAX; i += 256)
    if (hist[i] > 0) gbase[i] = atomicAdd(&bcur[i], hist[i]);
  __syncthreads();
#pragma unroll
  for (int i = 0; i < 16; i++) {
    if (r[i] >= 0) {
      int b = r[i] >> 8;
      int l = lofs[b] + atomicAdd(&pc[b], 1);
      stg[l] = ((long long)r[i] << 32) | (unsigned int)c[i];
      bkt[l] = (unsigned short)b;
    }
  }
  __syncthreads();
  for (int j = t; j < cntt; j += 256) {
    int b = bkt[j];
    ebuf[gbase[b] + (j - lofs[b])] = stg[j];
  }
}

// ---------- fused pass 2: per-bucket row-hist + local scan (off/cnt) + in-LDS adj
// build + trig/spc + node init + layer-0 pre. Replaces k_part2 + k_init16 and removes
// the N-wide off scan and per-row atomic counting entirely. ebuf ALIASES spc: ebuf is
// fully consumed (twice-read) before any spc write to the same index? NO — spc[abeg+k]
// is written in P3 while ebuf is still notionally live; but P2 copied all edges into
// LDS ladj first, so ebuf is DEAD after P2's read. P3 only reads ladj/lrow. Safe.
__global__ void __launch_bounds__(256) k_part2i(
    const int* __restrict__ bbase, int N, int E,
    const long long* __restrict__ ebuf,
    const float* __restrict__ posc,
    int* __restrict__ off, int* __restrict__ cnt, int* __restrict__ dhist,
    int* __restrict__ adj, float2* __restrict__ spc,
    const float* __restrict__ Wer, const float* __restrict__ wse, const float* __restrict__ bse,
    const float* __restrict__ Wmix, const float* __restrict__ Ws1, const float* __restrict__ bs1,
    const float* __restrict__ Wgate, const float* __restrict__ bgate,
    float* __restrict__ xr, float* __restrict__ xs, uint2* __restrict__ yzg) {
  __shared__ int lcnt[256], loff[256], lcur[256];
  __shared__ float lC[256], lS[256], lD[256], lpx[256], lpy[256];
  __shared__ int lh[DBINS];
  __shared__ int ladj[P2CAP];
  __shared__ unsigned char lrow[P2CAP];
  int t = threadIdx.x;
  int b = blockIdx.x;
  int r0 = b << 8;
  int abeg = bbase[b];
  int aend = bbase[b + 1];
  int sz = aend - abeg;
  bool haveRow = (r0 + t < N);
  lcnt[t] = 0;
  lC[t] = 0.f; lS[t] = 0.f; lD[t] = 0.f;
  if (t < DBINS) lh[t] = 0;
  if (haveRow) { lpx[t] = posc[2 * (r0 + t)]; lpy[t] = posc[2 * (r0 + t) + 1]; }
  __syncthreads();
  // P0: row histogram from ebuf slice
  for (int j = abeg + t; j < aend; j += 256)
    atomicAdd(&lcnt[(int)(ebuf[j] >> 32) - r0], 1);
  __syncthreads();
  // P1: exclusive 256-scan -> per-row offsets; write off/cnt (coalesced); degree hist
  int v = lcnt[t];
  loff[t] = v;
  __syncthreads();
  for (int o = 1; o < 256; o <<= 1) {
    int u = (t >= o) ? loff[t - o] : 0;
    __syncthreads();
    loff[t] += u;
    __syncthreads();
  }
  int myoff = loff[t] - v;
  __syncthreads();
  loff[t] = myoff;
  lcur[t] = myoff;
  if (haveRow) {
    off[r0 + t] = abeg + myoff;
    cnt[r0 + t] = v;
    atomicAdd(&lh[min(v, DBINS - 1)], 1);
  }
  if (t == 0 && r0 + 256 >= N) off[N] = E;
  __syncthreads();
  if (t < DBINS && lh[t] > 0) atomicAdd(&dhist[t], lh[t]);
  // P2: scatter into LDS adjacency (row order)
  if (sz <= P2CAP) {
    for (int j = abeg + t; j < aend; j += 256) {
      long long p = ebuf[j];
      int cl = (int)(unsigned int)(p & 0xffffffffLL);
      int rr = (int)(p >> 32) - r0;
      int l = atomicAdd(&lcur[rr], 1);
      ladj[l] = cl;
      lrow[l] = (unsigned char)rr;
    }
    __syncthreads();
    // P3: coalesced adj+spc write, per-row C/S/D accumulation (LDS atomics)
    for (int k = t; k < sz; k += 256) {
      int cl = ladj[k];
      int rr = lrow[k];
      adj[abeg + k] = cl;
      float dx = lpx[rr] - posc[2 * cl + 0];
      float dy = lpy[rr] - posc[2 * cl + 1];
      float d = sqrtf(dx * dx + dy * dy);
      float sp, cp;
      sincospif(d, &sp, &cp);
      spc[abeg + k] = make_float2(1.41421356237309515f * sp / (d + 1e-8f), 2.0f * cp);
      float invd = (d > 0.f) ? 1.f / d : 0.f;
      atomicAdd(&lC[rr], (d > 0.f) ? dx * invd : 1.0f);
      atomicAdd(&lS[rr], dy * invd);
      atomicAdd(&lD[rr], d);
    }
  } else {
    // degenerate bucket (>P2CAP edges; ~96 sigma for random graphs): global scatter
    for (int j = abeg + t; j < aend; j += 256) {
      long long p = ebuf[j];
      int cl = (int)(unsigned int)(p & 0xffffffffLL);
      int rr = (int)(p >> 32) - r0;
      int l = abeg + atomicAdd(&lcur[rr], 1);
      adj[l] = cl;
      float dx = lpx[rr] - posc[2 * cl + 0];
      float dy = lpy[rr] - posc[2 * cl + 1];
      float d = sqrtf(dx * dx + dy * dy);
      float sp, cp;
      sincospif(d, &sp, &cp);
      spc[l] = make_float2(1.41421356237309515f * sp / (d + 1e-8f), 2.0f * cp);
      float invd = (d > 0.f) ? 1.f / d : 0.f;
      atomicAdd(&lC[rr], (d > 0.f) ? dx * invd : 1.0f);
      atomicAdd(&lS[rr], dy * invd);
      atomicAdd(&lD[rr], d);
    }
  }
  __syncthreads();
  // P4: node init + fused layer-0 pre; 16 lanes/node, 16 rounds of 16 nodes
  int r = t & 15;
  float wmxn[16], wsan[16], wgtn[16];
#pragma unroll
  for (int q = 0; q < 16; q++) wmxn[q] = Wmix[r * 16 + q];
#pragma unroll
  for (int q = 0; q < 16; q++) wsan[q] = Ws1[q * 16 + r];
#pragma unroll
  for (int q = 0; q < 16; q++) wgtn[q] = Wgate[q * 16 + r];
  float w0 = Wer[2 * r], w1 = Wer[2 * r + 1];
  for (int round = 0; round < 16; round++) {
    int node = (round << 4) + (t >> 4);
    int n = r0 + node;
    if (n >= N) continue;                 // n uniform within each 16-lane group
    float id = 1.0f / fmaxf((float)lcnt[node], 1.0f);
    float C = lC[node] * id, S = lS[node] * id, dm = lD[node] * id;
    float2 x;
    x.x = C * w0 - S * w1;
    x.y = S * w0 + C * w1;
    ((float2*)xr)[(size_t)n * 16 + r] = x;
    float s_new = leaky(dm * wse[r] + bse[r]);
    xs[(size_t)n * 16 + r] = s_new;
    float y0 = 0.f, y1 = 0.f;
    float z = bs1[r], gtn = bgate[r];
#pragma unroll
    for (int j = 0; j < 16; j++) {
      float xj0 = __shfl(x.x, j, 16);
      float xj1 = __shfl(x.y, j, 16);
      float sj  = __shfl(s_new, j, 16);
      y0 += wmxn[j] * xj0;
      y1 += wmxn[j] * xj1;
      z  += wsan[j] * sj;
      gtn += wgtn[j] * sj;
    }
    gtn = 1.0f / (1.0f + __expf(-gtn));
    __half2 hA = __floats2half2_rn(y0, y1);
    __half2 hB = __floats2half2_rn(z, gtn);
    uint2 w2;
    w2.x = *(unsigned int*)&hA;
    w2.y = *(unsigned int*)&hB;
    yzg[(size_t)n * 16 + r] = w2;
  }
}

// ---------- degree-sort perm fill (dhist 64-scan re-derived per block) ----------
__global__ void k_permfill(int N, const int* __restrict__ cnt,
                           const int* __restrict__ dhist,
                           int* __restrict__ dcur, int* __restrict__ perm) {
  __shared__ int sd[DBINS], dbase[DBINS];
  __shared__ int lh[DBINS], base[DBINS];
  int t = threadIdx.x;
  int dv = 0;
  if (t < DBINS) { dv = dhist[t]; sd[t] = dv; lh[t] = 0; }
  __syncthreads();
  for (int o = 1; o < DBINS; o <<= 1) {
    int u = (t >= o && t < DBINS) ? sd[t - o] : 0;
    __syncthreads();
    if (t < DBINS) sd[t] += u;
    __syncthreads();
  }
  if (t < DBINS) dbase[t] = sd[t] - dv;
  __syncthreads();
  int i = blockIdx.x * 1024 + t;
  int b = 0, lr = 0;
  if (i < N) {
    b = min(cnt[i], DBINS - 1);
    lr = atomicAdd(&lh[b], 1);
  }
  __syncthreads();
  if (t < DBINS && lh[t] > 0) base[t] = dbase[t] + atomicAdd(&dcur[t], lh[t]);
  __syncthreads();
  if (i < N) perm[base[b] + lr] = i;
}

// ---------- EqBlock layer + fused next-layer pre (unchanged from r7) ----------
__global__ void __launch_bounds__(256) k_layer(
    int N, const int* __restrict__ off,
    const int* __restrict__ adj, const float2* __restrict__ spc,
    const uint2* __restrict__ yzg, const int* __restrict__ perm,
    const float* __restrict__ Wg, const float* __restrict__ bg,
    const float* __restrict__ Ws1,   // this layer; demb rows are 16..31
    float* xr, float* xs,
    int write_next, uint2* __restrict__ yzg_out,
    const float* __restrict__ Wmixn, const float* __restrict__ Ws1n,
    const float* __restrict__ bs1n,
    const float* __restrict__ Wgaten, const float* __restrict__ bgaten) {
  int idx = blockIdx.x * 256 + threadIdx.x;
  int g = idx >> 4, r = idx & 15;
  if (g >= N) return;
  int n = perm[g];                      // degree-sorted: waves get equal-degree nodes
  float wg[16], ws[16];
#pragma unroll
  for (int q = 0; q < 16; q++) wg[q] = Wg[q * 16 + r];
#pragma unroll
  for (int q = 0; q < 16; q++) ws[q] = Ws1[(16 + q) * 16 + r];
  float bgr = bg[r];

  int a = off[n], bnd = off[n + 1];
  float acc0 = 0.f, acc1 = 0.f, accs = 0.f;
  if (a < bnd) {
    int last = bnd - 1;
    int    c0 = adj[a];               float2 p0 = spc[a];
    int    c1 = adj[min(a + 1, last)]; float2 p1 = spc[min(a + 1, last)];
    int    cn = adj[min(a + 2, last)]; float2 p2 = spc[min(a + 2, last)];
    uint2 Y0 = yzg[(c0 << 4) + r];
    uint2 Y1 = yzg[(c1 << 4) + r];
    int k = a;
    for (; k + 3 < bnd; k++) {
      int c3 = adj[k + 3];
      float2 p3 = spc[k + 3];
      uint2 Y2 = yzg[(cn << 4) + r];
      float skm1 = 0.f, sk = p0.x, c2 = p0.y;
      float g1 = bgr, dot = 0.f;
#pragma unroll
      for (int q = 0; q < RDIM; q++) {
        g1  = __builtin_fmaf(sk, wg[q], g1);
        dot = __builtin_fmaf(sk, ws[q], dot);
        float sn = __builtin_fmaf(c2, sk, -skm1);
        skm1 = sk; sk = sn;
      }
      float2 f01 = __half22float2(*(__half2*)&Y0.x);
      float2 fzg = __half22float2(*(__half2*)&Y0.y);
      acc0 = __builtin_fmaf(g1, f01.x, acc0);
      acc1 = __builtin_fmaf(g1, f01.y, acc1);
      accs += leaky(dot + fzg.x);
      c0 = c1; p0 = p1; c1 = cn; p1 = p2; cn = c3; p2 = p3; Y0 = Y1; Y1 = Y2;
    }
    for (; k < bnd; k++) {
      uint2 Y2 = Y1;
      if (k + 2 < bnd) Y2 = yzg[(cn << 4) + r];
      float skm1 = 0.f, sk = p0.x, c2 = p0.y;
      float g1 = bgr, dot = 0.f;
#pragma unroll
      for (int q = 0; q < RDIM; q++) {
        g1  = __builtin_fmaf(sk, wg[q], g1);
        dot = __builtin_fmaf(sk, ws[q], dot);
        float sn = __builtin_fmaf(c2, sk, -skm1);
        skm1 = sk; sk = sn;
      }
      float2 f01 = __half22float2(*(__half2*)&Y0.x);
      float2 fzg = __half22float2(*(__half2*)&Y0.y);
      acc0 = __builtin_fmaf(g1, f01.x, acc0);
      acc1 = __builtin_fmaf(g1, f01.y, acc1);
      accs += leaky(dot + fzg.x);
      c0 = c1; p0 = p1; c1 = cn; p1 = p2; Y0 = Y1; Y1 = Y2;
    }
  }
  float id = 1.0f / fmaxf((float)(bnd - a), 1.0f);
  uint2 Yg = yzg[(n << 4) + r];
  float gt = __half22float2(*(__half2*)&Yg.y).y;
  float2* xr2 = (float2*)xr;
  float2 x = xr2[(n << 4) + r];
  x.x += acc0 * id * gt;
  x.y += acc1 * id * gt;
  xr2[(n << 4) + r] = x;                // in-place safe: (n,r) written only by this thread
  float s_new = xs[(n << 4) + r] + accs * id;
  xs[(n << 4) + r] = s_new;

  if (write_next) {
    float wmxn[16], wsan[16], wgtn[16];
#pragma unroll
    for (int q = 0; q < 16; q++) wmxn[q] = Wmixn[r * 16 + q];
#pragma unroll
    for (int q = 0; q < 16; q++) wsan[q] = Ws1n[q * 16 + r];
#pragma unroll
    for (int q = 0; q < 16; q++) wgtn[q] = Wgaten[q * 16 + r];
    float y0 = 0.f, y1 = 0.f;
    float z = bs1n[r], gtn = bgaten[r];
#pragma unroll
    for (int j = 0; j < 16; j++) {
      float xj0 = __shfl(x.x, j, 16);
      float xj1 = __shfl(x.y, j, 16);
      float sj  = __shfl(s_new, j, 16);
      y0 += wmxn[j] * xj0;
      y1 += wmxn[j] * xj1;
      z  += wsan[j] * sj;
      gtn += wgtn[j] * sj;
    }
    gtn = 1.0f / (1.0f + __expf(-gtn));
    __half2 hA = __floats2half2_rn(y0, y1);
    __half2 hB = __floats2half2_rn(z, gtn);
    uint2 w2;
    w2.x = *(unsigned int*)&hA;
    w2.y = *(unsigned int*)&hB;
    yzg_out[(n << 4) + r] = w2;
  }
}

// ---------- final rotate-out + MLP + binned graph sum (unchanged from r7) ----------
__global__ void __launch_bounds__(128) k_final(
    int N, const float* __restrict__ xr, const float* __restrict__ xs,
    const float* __restrict__ cthn, const float* __restrict__ sthn,
    const int* __restrict__ batch,
    const float* __restrict__ W1, const float* __restrict__ b1,
    const float* __restrict__ W2, const float* __restrict__ b2,
    float* __restrict__ out) {
  __shared__ float obin[320 * 6];
  int t = threadIdx.x;
  int start = blockIdx.x * 128;
  int n = start + t;
  int b0 = batch[min(start, N - 1)];
  int span = batch[min(start + 127, N - 1)] - b0;
  bool useLds = (span < 320);
  if (useLds) for (int i = t; i < (span + 1) * 6; i += 128) obin[i] = 0.f;
  __syncthreads();

  float u[NC];
  bool act = (n < N);
  if (act) {
    float xc[48];
    const float4* xs4 = (const float4*)(xs + (size_t)n * NS);
#pragma unroll
    for (int j = 0; j < 4; j++) {
      float4 v = xs4[j];
      xc[4 * j + 0] = v.x; xc[4 * j + 1] = v.y; xc[4 * j + 2] = v.z; xc[4 * j + 3] = v.w;
    }
    float c = cthn[n], s = sthn[n];
    const float4* xr4 = (const float4*)(xr + (size_t)n * 32);
#pragma unroll
    for (int j = 0; j < 8; j++) {
      float4 v = xr4[j];
      xc[16 + 4 * j + 0] = c * v.x - s * v.y;
      xc[16 + 4 * j + 1] = s * v.x + c * v.y;
      xc[16 + 4 * j + 2] = c * v.z - s * v.w;
      xc[16 + 4 * j + 3] = s * v.z + c * v.w;
    }
#pragma unroll
    for (int q = 0; q < NC; q++) u[q] = b2[q];
    for (int h = 0; h < H1; h += 4) {
      float a0 = b1[h + 0], a1 = b1[h + 1], a2 = b1[h + 2], a3 = b1[h + 3];
#pragma unroll
      for (int q = 0; q < 48; q++) {
        float4 w = *(const float4*)(W1 + (size_t)q * H1 + h);
        float x = xc[q];
        a0 = __builtin_fmaf(x, w.x, a0);
        a1 = __builtin_fmaf(x, w.y, a1);
        a2 = __builtin_fmaf(x, w.z, a2);
        a3 = __builtin_fmaf(x, w.w, a3);
      }
      a0 = leaky(a0); a1 = leaky(a1); a2 = leaky(a2); a3 = leaky(a3);
#pragma unroll
      for (int q = 0; q < NC; q++)
        u[q] += a0 * W2[(h + 0) * 6 + q] + a1 * W2[(h + 1) * 6 + q]
              + a2 * W2[(h + 2) * 6 + q] + a3 * W2[(h + 3) * 6 + q];
    }
  }
  if (useLds) {
    if (act) {
      int rb = batch[n] - b0;
#pragma unroll
      for (int q = 0; q < NC; q++) atomicAdd(&obin[rb * 6 + q], u[q]);
    }
    __syncthreads();
    for (int i = t; i < (span + 1) * 6; i += 128) atomicAdd(&out[b0 * 6 + i], obin[i]);
  } else if (act) {
    int b = batch[n];
#pragma unroll
    for (int q = 0; q < NC; q++) atomicAdd(&out[b * 6 + q], u[q]);
  }
}

extern "C" void kernel_launch(void* const* d_in, const int* in_sizes, int n_in,
                              void* d_out, int out_size, void* d_ws, size_t ws_size,
                              hipStream_t stream) {
  const float* pos   = (const float*)d_in[0];
  const float* Wer   = (const float*)d_in[1];
  const float* wse   = (const float*)d_in[2];
  const float* bse   = (const float*)d_in[3];
  const float* Wg    = (const float*)d_in[4];
  const float* bg    = (const float*)d_in[5];
  const float* Wmix  = (const float*)d_in[6];
  const float* Wgate = (const float*)d_in[7];
  const float* bgate = (const float*)d_in[8];
  const float* Ws1   = (const float*)d_in[9];
  const float* bs1   = (const float*)d_in[10];
  const float* W1    = (const float*)d_in[11];
  const float* b1    = (const float*)d_in[12];
  const float* W2    = (const float*)d_in[13];
  const float* b2    = (const float*)d_in[14];
  const int*   ei    = (const int*)d_in[15];
  const int*   batch = (const int*)d_in[16];
  float* out = (float*)d_out;

  int N = in_sizes[0] / 2;
  int E = in_sizes[15] / 2;
  int G = out_size / NC;
  int NB = (N + 255) / 256;   // 256-row buckets (requires NB <= NBMAX)

  // ---- workspace layout (~67 MB; ebuf aliases spc) ----
  float* W = (float*)d_ws;
  size_t o = 0;
  float* gsum   = W + o; o += (size_t)2 * G;
  float* gcnt   = W + o; o += (size_t)G;
  int*   bhist  = (int*)(W + o); o += (size_t)NBMAX;
  int*   dhist  = (int*)(W + o); o += (size_t)DBINS;
  int*   dcur   = (int*)(W + o); o += (size_t)DBINS;
  size_t zero_bytes = o * 4;
  o = (o + 3) & ~(size_t)3;
  float* posc   = W + o; o += (size_t)2 * N;
  float* cthn   = W + o; o += (size_t)N;
  float* sthn   = W + o; o += (size_t)N;
  int*   off    = (int*)(W + o); o += (size_t)N + 1; o = (o + 3) & ~(size_t)3;
  int*   bbase  = (int*)(W + o); o += (size_t)NBMAX + 1;
  int*   bcur   = (int*)(W + o); o += (size_t)NBMAX;
  int*   cnt    = (int*)(W + o); o += (size_t)N;
  int*   perm   = (int*)(W + o); o += (size_t)N; o = (o + 3) & ~(size_t)3;
  int*   adj    = (int*)(W + o); o += (size_t)E; o = (o + 1) & ~(size_t)1;
  float2* spc   = (float2*)(W + o); o += (size_t)2 * E;
  long long* ebuf = (long long*)spc;   // ALIAS: ebuf dead after k_part2i's P2 read
  uint2* yzgA   = (uint2*)(W + o); o += (size_t)32 * N;
  uint2* yzgB   = (uint2*)(W + o); o += (size_t)32 * N;
  float* xr     = W + o; o += (size_t)N * 32;
  float* xs     = W + o; o += (size_t)N * 16;
  (void)ws_size;

  hipMemsetAsync(d_ws, 0, zero_bytes, stream);
  hipMemsetAsync(d_out, 0, (size_t)out_size * 4, stream);

  int nbN  = (N + 255) / 256;
  int nbT  = (E + TILE - 1) / TILE;
  int nbG  = nbT > nbN ? nbT : nbN;
  int nbN16 = ((size_t)N * 16 + 255) / 256;
  int nbP  = (N + 1023) / 1024;
  int nbF  = (N + 127) / 128;

  k_gsum_bhist<<<nbG, 256, 0, stream>>>(pos, batch, N, gsum, gcnt, ei, E, bhist);
  k_center_bscan<<<nbN, 256, 0, stream>>>(pos, batch, N, E, gsum, gcnt,
                                          posc, cthn, sthn, bhist, bbase, bcur, NB);
  k_part1<<<nbT, 256, 0, stream>>>(ei, E, bcur, ebuf);
  k_part2i<<<NB, 256, 0, stream>>>(bbase, N, E, ebuf, posc,
                                   off, cnt, dhist, adj, spc,
                                   Wer, wse, bse, Wmix, Ws1, bs1, Wgate, bgate,
                                   xr, xs, yzgA);
  k_permfill<<<nbP, 1024, 0, stream>>>(N, cnt, dhist, dcur, perm);

  // layer 0: read A, write B (fused pre for layer 1)
  k_layer<<<nbN16, 256, 0, stream>>>(N, off, adj, spc, yzgA, perm,
                                     Wg, bg, Ws1, xr, xs,
                                     1, yzgB,
                                     Wmix + 256, Ws1 + 512, bs1 + 16, Wgate + 256, bgate + 16);
  // layer 1: read B, write A (fused pre for layer 2)
  k_layer<<<nbN16, 256, 0, stream>>>(N, off, adj, spc, yzgB, perm,
                                     Wg + 256, bg + 16, Ws1 + 512, xr, xs,
                                     1, yzgA,
                                     Wmix + 512, Ws1 + 1024, bs1 + 32, Wgate + 512, bgate + 32);
  // layer 2: read A, no next
  k_layer<<<nbN16, 256, 0, stream>>>(N, off, adj, spc, yzgA, perm,
                                     Wg + 512, bg + 32, Ws1 + 1024, xr, xs,
                                     0, yzgB,
                                     Wmix, Ws1, bs1, Wgate, bgate);

  k_final<<<nbF, 128, 0, stream>>>(N, xr, xs, cthn, sthn, batch, W1, b1, W2, b2, out);
}

// Round 9
// 412.471 us; speedup vs baseline: 1.5281x; 1.0818x over previous
//
#include <hip/hip_runtime.h>
#include <hip/hip_fp16.h>
#include <math.h>

#define NREP 16
#define RDIM 16
#define NS   16
#define NC   6
#define H1   144
#define DBINS 64
#define TILE 4096
#define NBMAX 512     // max 256-row buckets supported (N <= 131072)
#define P2CAP 10240   // bucket LDS adj capacity; mean bucket = 4096 edges

static __device__ __forceinline__ float leaky(float v) { return v > 0.0f ? v : 0.01f * v; }

// ---------- fused: per-graph mean (LDS-binned) + LDS-aggregated bucket histogram ----------
__global__ void __launch_bounds__(256) k_gsum_bhist(
    const float* __restrict__ pos, const int* __restrict__ batch, int N,
    float* __restrict__ gsum, float* __restrict__ gcnt,
    const int* __restrict__ ei, int E, int* __restrict__ bhist) {
  int t = threadIdx.x;
  __shared__ int h[NBMAX];
  for (int i = t; i < NBMAX; i += 256) h[i] = 0;
  __syncthreads();
  int base = blockIdx.x * TILE;
  int lim = min(base + TILE, E);
  for (int j = base + t; j < lim; j += 256) atomicAdd(&h[ei[j] >> 8], 1);
  __syncthreads();
  for (int i = t; i < NBMAX; i += 256)
    if (h[i] > 0) atomicAdd(&bhist[i], h[i]);

  __shared__ float bx[320], by[320], bc[320];
  int start = blockIdx.x * 256;
  if (start >= N) return;
  int n = start + t;
  int b0 = batch[min(start, N - 1)];
  int span = batch[min(start + 255, N - 1)] - b0;
  bool useLds = (span < 320);
  if (useLds) {
    for (int i = t; i <= span; i += 256) { bx[i] = 0.f; by[i] = 0.f; bc[i] = 0.f; }
    __syncthreads();
    if (n < N) {
      int rb = batch[n] - b0;
      atomicAdd(&bx[rb], pos[2 * n + 0]);
      atomicAdd(&by[rb], pos[2 * n + 1]);
      atomicAdd(&bc[rb], 1.0f);
    }
    __syncthreads();
    for (int i = t; i <= span; i += 256) {
      if (bc[i] != 0.0f) {
        atomicAdd(&gsum[2 * (b0 + i) + 0], bx[i]);
        atomicAdd(&gsum[2 * (b0 + i) + 1], by[i]);
        atomicAdd(&gcnt[b0 + i], bc[i]);
      }
    }
  } else if (n < N) {
    int b = batch[n];
    atomicAdd(&gsum[2 * b + 0], pos[2 * n + 0]);
    atomicAdd(&gsum[2 * b + 1], pos[2 * n + 1]);
    atomicAdd(&gcnt[b], 1.0f);
  }
}

// ---------- center (elementwise) + block0: bucket-base scan ----------
__global__ void __launch_bounds__(256) k_center_bscan(
    const float* __restrict__ pos, const int* __restrict__ batch, int N, int E,
    const float* __restrict__ gsum, const float* __restrict__ gcnt,
    float* __restrict__ posc, float* __restrict__ cthn, float* __restrict__ sthn,
    const int* __restrict__ bhist, int* __restrict__ bbase, int* __restrict__ bcur, int NB) {
  int t = threadIdx.x;
  if (blockIdx.x == 0) {
    __shared__ int s[NBMAX];
    int v0 = (t < NB) ? bhist[t] : 0;
    int v1 = (t + 256 < NB) ? bhist[t + 256] : 0;
    s[t] = v0; s[t + 256] = v1;
    __syncthreads();
    for (int o = 1; o < NBMAX; o <<= 1) {
      int a0 = (t >= o) ? s[t - o] : 0;
      int a1 = s[t + 256 - o];
      __syncthreads();
      s[t] += a0; s[t + 256] += a1;
      __syncthreads();
    }
    if (t < NB)       { int ex = s[t] - v0;       bbase[t] = ex;       bcur[t] = ex; }
    if (t + 256 < NB) { int ex = s[t + 256] - v1; bbase[t + 256] = ex; bcur[t + 256] = ex; }
    if (t == 0) bbase[NB] = E;
  }
  int i = blockIdx.x * 256 + t;
  if (i < N) {
    int b = batch[i];
    float invc = 1.0f / fmaxf(gcnt[b], 1.0f);
    float px = pos[2 * i + 0] - gsum[2 * b + 0] * invc;
    float py = pos[2 * i + 1] - gsum[2 * b + 1] * invc;
    posc[2 * i + 0] = px;
    posc[2 * i + 1] = py;
    float r = sqrtf(px * px + py * py);
    if (r > 0.0f) { cthn[i] = px / r; sthn[i] = py / r; }
    else          { cthn[i] = 1.0f;  sthn[i] = 0.0f; }
  }
}

// ---------- CSR build pass 1: bucket-partition edges by row>>8 ----------
__global__ void __launch_bounds__(256) k_part1(
    const int* __restrict__ ei, int E,
    int* __restrict__ bcur, long long* __restrict__ ebuf) {
  __shared__ int hist[NBMAX], lofs[NBMAX], gbase[NBMAX], pc[NBMAX];
  __shared__ long long stg[TILE];
  __shared__ unsigned short bkt[TILE];
  int t = threadIdx.x;
  int base = blockIdx.x * TILE;
  int cntt = min(TILE, E - base);
  for (int i = t; i < NBMAX; i += 256) { hist[i] = 0; pc[i] = 0; }
  __syncthreads();
  int r[16], c[16];
#pragma unroll
  for (int i = 0; i < 16; i++) {
    int e = base + t + i * 256;
    r[i] = -1;
    if (e < E) {
      r[i] = ei[e];
      c[i] = ei[E + e];
      atomicAdd(&hist[r[i] >> 8], 1);
    }
  }
  __syncthreads();
  lofs[t] = hist[t]; lofs[t + 256] = hist[t + 256];
  __syncthreads();
  for (int o = 1; o < NBMAX; o <<= 1) {
    int a0 = (t >= o) ? lofs[t - o] : 0;
    int a1 = lofs[t + 256 - o];
    __syncthreads();
    lofs[t] += a0; lofs[t + 256] += a1;
    __syncthreads();
  }
  int e0 = lofs[t] - hist[t], e1 = lofs[t + 256] - hist[t + 256];
  __syncthreads();
  lofs[t] = e0; lofs[t + 256] = e1;
  __syncthreads();
  for (int i = t; i < NBMAX; i += 256)
    if (hist[i] > 0) gbase[i] = atomicAdd(&bcur[i], hist[i]);
  __syncthreads();
#pragma unroll
  for (int i = 0; i < 16; i++) {
    if (r[i] >= 0) {
      int b = r[i] >> 8;
      int l = lofs[b] + atomicAdd(&pc[b], 1);
      stg[l] = ((long long)r[i] << 32) | (unsigned int)c[i];
      bkt[l] = (unsigned short)b;
    }
  }
  __syncthreads();
  for (int j = t; j < cntt; j += 256) {
    int b = bkt[j];
    ebuf[gbase[b] + (j - lofs[b])] = stg[j];
  }
}

// ---------- lean pass 2: per-bucket row-hist + local scan (off/cnt/dhist) + in-LDS adj ----------
// r8 post-mortem: fusing the per-edge trig/init (random posc gathers) into this 392-block,
// 2-blocks/CU kernel left it latency-bound (occ 13.5%, VALU 10.5%). Split: this kernel keeps
// only the LDS permutation work (no random global loads). Dropping lrow cuts LDS to ~43KB
// -> 3 blocks/CU. The latency-sensitive per-edge work moves back to high-occupancy k_init16.
__global__ void __launch_bounds__(256) k_part2(
    const int* __restrict__ bbase, int N, int E,
    const long long* __restrict__ ebuf,
    int* __restrict__ off, int* __restrict__ cnt, int* __restrict__ dhist,
    int* __restrict__ adj) {
  __shared__ int lcnt[256], loff[256], lcur[256];
  __shared__ int lh[DBINS];
  __shared__ int ladj[P2CAP];
  int t = threadIdx.x;
  int b = blockIdx.x;
  int r0 = b << 8;
  int abeg = bbase[b];
  int aend = bbase[b + 1];
  int sz = aend - abeg;
  bool haveRow = (r0 + t < N);
  lcnt[t] = 0;
  if (t < DBINS) lh[t] = 0;
  __syncthreads();
  // P0: row histogram from ebuf slice
  for (int j = abeg + t; j < aend; j += 256)
    atomicAdd(&lcnt[(int)(ebuf[j] >> 32) - r0], 1);
  __syncthreads();
  // P1: exclusive 256-scan -> per-row offsets; write off/cnt; degree hist
  int v = lcnt[t];
  loff[t] = v;
  __syncthreads();
  for (int o = 1; o < 256; o <<= 1) {
    int u = (t >= o) ? loff[t - o] : 0;
    __syncthreads();
    loff[t] += u;
    __syncthreads();
  }
  int myoff = loff[t] - v;
  __syncthreads();
  loff[t] = myoff;
  lcur[t] = myoff;
  if (haveRow) {
    off[r0 + t] = abeg + myoff;
    cnt[r0 + t] = v;
    atomicAdd(&lh[min(v, DBINS - 1)], 1);
  }
  if (t == 0 && r0 + 256 >= N) off[N] = E;
  __syncthreads();
  if (t < DBINS && lh[t] > 0) atomicAdd(&dhist[t], lh[t]);
  // P2: scatter into LDS adjacency (row order), then coalesced global write
  if (sz <= P2CAP) {
    for (int j = abeg + t; j < aend; j += 256) {
      long long p = ebuf[j];
      int cl = (int)(unsigned int)(p & 0xffffffffLL);
      int rr = (int)(p >> 32) - r0;
      ladj[atomicAdd(&lcur[rr], 1)] = cl;
    }
    __syncthreads();
    for (int j = t; j < sz; j += 256) adj[abeg + j] = ladj[j];
  } else {
    // degenerate bucket (>P2CAP edges): direct global scatter
    for (int j = abeg + t; j < aend; j += 256) {
      long long p = ebuf[j];
      int cl = (int)(unsigned int)(p & 0xffffffffLL);
      int rr = (int)(p >> 32) - r0;
      adj[abeg + atomicAdd(&lcur[rr], 1)] = cl;
    }
  }
}

// ---------- fused node init + per-edge trig fill + layer-0 pre (r7-proven, high-occ) ----------
__global__ void __launch_bounds__(256) k_init16(
    int N, const int* __restrict__ off, const int* __restrict__ adj,
    const float* __restrict__ posc, float2* __restrict__ spc,
    const float* __restrict__ Wer, const float* __restrict__ wse, const float* __restrict__ bse,
    const float* __restrict__ Wmix, const float* __restrict__ Ws1, const float* __restrict__ bs1,
    const float* __restrict__ Wgate, const float* __restrict__ bgate,
    float* __restrict__ xr, float* __restrict__ xs, uint2* __restrict__ yzg) {
  int idx = blockIdx.x * 256 + threadIdx.x;
  int n = idx >> 4, r = idx & 15;
  if (n >= N) return;
  int a = off[n], b = off[n + 1];
  float px = posc[2 * n + 0], py = posc[2 * n + 1];
  float C = 0.f, S = 0.f, D = 0.f;
  for (int k = a + r; k < b; k += 16) {
    int cl = adj[k];
    float dx = px - posc[2 * cl + 0];
    float dy = py - posc[2 * cl + 1];
    float d = sqrtf(dx * dx + dy * dy);
    float sp, cp;
    sincospif(d, &sp, &cp);
    float spp = 1.41421356237309515f * sp / (d + 1e-8f);
    spc[k] = make_float2(spp, 2.0f * cp);
    if (d > 0.0f) {
      float inv = 1.0f / d;
      C += dx * inv;
      S += dy * inv;
    } else {
      C += 1.0f;
    }
    D += d;
  }
#pragma unroll
  for (int o = 1; o < 16; o <<= 1) {
    C += __shfl_xor(C, o, 16);
    S += __shfl_xor(S, o, 16);
    D += __shfl_xor(D, o, 16);
  }
  float id = 1.0f / fmaxf((float)(b - a), 1.0f);
  C *= id; S *= id;
  float dm = D * id;
  float w0 = Wer[2 * r], w1 = Wer[2 * r + 1];
  float2 x;
  x.x = C * w0 - S * w1;
  x.y = S * w0 + C * w1;
  ((float2*)xr)[(size_t)n * 16 + r] = x;
  float s_new = leaky(dm * wse[r] + bse[r]);
  xs[(size_t)n * 16 + r] = s_new;

  float wmxn[16], wsan[16], wgtn[16];
#pragma unroll
  for (int q = 0; q < 16; q++) wmxn[q] = Wmix[r * 16 + q];
#pragma unroll
  for (int q = 0; q < 16; q++) wsan[q] = Ws1[q * 16 + r];
#pragma unroll
  for (int q = 0; q < 16; q++) wgtn[q] = Wgate[q * 16 + r];
  float y0 = 0.f, y1 = 0.f;
  float z = bs1[r], gtn = bgate[r];
#pragma unroll
  for (int j = 0; j < 16; j++) {
    float xj0 = __shfl(x.x, j, 16);
    float xj1 = __shfl(x.y, j, 16);
    float sj  = __shfl(s_new, j, 16);
    y0 += wmxn[j] * xj0;
    y1 += wmxn[j] * xj1;
    z  += wsan[j] * sj;
    gtn += wgtn[j] * sj;
  }
  gtn = 1.0f / (1.0f + __expf(-gtn));
  __half2 hA = __floats2half2_rn(y0, y1);
  __half2 hB = __floats2half2_rn(z, gtn);
  uint2 w2;
  w2.x = *(unsigned int*)&hA;
  w2.y = *(unsigned int*)&hB;
  yzg[(size_t)n * 16 + r] = w2;
}

// ---------- degree-sort perm fill ----------
__global__ void k_permfill(int N, const int* __restrict__ cnt,
                           const int* __restrict__ dhist,
                           int* __restrict__ dcur, int* __restrict__ perm) {
  __shared__ int sd[DBINS], dbase[DBINS];
  __shared__ int lh[DBINS], base[DBINS];
  int t = threadIdx.x;
  int dv = 0;
  if (t < DBINS) { dv = dhist[t]; sd[t] = dv; lh[t] = 0; }
  __syncthreads();
  for (int o = 1; o < DBINS; o <<= 1) {
    int u = (t >= o && t < DBINS) ? sd[t - o] : 0;
    __syncthreads();
    if (t < DBINS) sd[t] += u;
    __syncthreads();
  }
  if (t < DBINS) dbase[t] = sd[t] - dv;
  __syncthreads();
  int i = blockIdx.x * 1024 + t;
  int b = 0, lr = 0;
  if (i < N) {
    b = min(cnt[i], DBINS - 1);
    lr = atomicAdd(&lh[b], 1);
  }
  __syncthreads();
  if (t < DBINS && lh[t] > 0) base[t] = dbase[t] + atomicAdd(&dcur[t], lh[t]);
  __syncthreads();
  if (i < N) perm[base[b] + lr] = i;
}

// ---------- EqBlock layer + fused next-layer pre (unchanged) ----------
__global__ void __launch_bounds__(256) k_layer(
    int N, const int* __restrict__ off,
    const int* __restrict__ adj, const float2* __restrict__ spc,
    const uint2* __restrict__ yzg, const int* __restrict__ perm,
    const float* __restrict__ Wg, const float* __restrict__ bg,
    const float* __restrict__ Ws1,   // this layer; demb rows are 16..31
    float* xr, float* xs,
    int write_next, uint2* __restrict__ yzg_out,
    const float* __restrict__ Wmixn, const float* __restrict__ Ws1n,
    const float* __restrict__ bs1n,
    const float* __restrict__ Wgaten, const float* __restrict__ bgaten) {
  int idx = blockIdx.x * 256 + threadIdx.x;
  int g = idx >> 4, r = idx & 15;
  if (g >= N) return;
  int n = perm[g];
  float wg[16], ws[16];
#pragma unroll
  for (int q = 0; q < 16; q++) wg[q] = Wg[q * 16 + r];
#pragma unroll
  for (int q = 0; q < 16; q++) ws[q] = Ws1[(16 + q) * 16 + r];
  float bgr = bg[r];

  int a = off[n], bnd = off[n + 1];
  float acc0 = 0.f, acc1 = 0.f, accs = 0.f;
  if (a < bnd) {
    int last = bnd - 1;
    int    c0 = adj[a];               float2 p0 = spc[a];
    int    c1 = adj[min(a + 1, last)]; float2 p1 = spc[min(a + 1, last)];
    int    cn = adj[min(a + 2, last)]; float2 p2 = spc[min(a + 2, last)];
    uint2 Y0 = yzg[(c0 << 4) + r];
    uint2 Y1 = yzg[(c1 << 4) + r];
    int k = a;
    for (; k + 3 < bnd; k++) {
      int c3 = adj[k + 3];
      float2 p3 = spc[k + 3];
      uint2 Y2 = yzg[(cn << 4) + r];
      float skm1 = 0.f, sk = p0.x, c2 = p0.y;
      float g1 = bgr, dot = 0.f;
#pragma unroll
      for (int q = 0; q < RDIM; q++) {
        g1  = __builtin_fmaf(sk, wg[q], g1);
        dot = __builtin_fmaf(sk, ws[q], dot);
        float sn = __builtin_fmaf(c2, sk, -skm1);
        skm1 = sk; sk = sn;
      }
      float2 f01 = __half22float2(*(__half2*)&Y0.x);
      float2 fzg = __half22float2(*(__half2*)&Y0.y);
      acc0 = __builtin_fmaf(g1, f01.x, acc0);
      acc1 = __builtin_fmaf(g1, f01.y, acc1);
      accs += leaky(dot + fzg.x);
      c0 = c1; p0 = p1; c1 = cn; p1 = p2; cn = c3; p2 = p3; Y0 = Y1; Y1 = Y2;
    }
    for (; k < bnd; k++) {
      uint2 Y2 = Y1;
      if (k + 2 < bnd) Y2 = yzg[(cn << 4) + r];
      float skm1 = 0.f, sk = p0.x, c2 = p0.y;
      float g1 = bgr, dot = 0.f;
#pragma unroll
      for (int q = 0; q < RDIM; q++) {
        g1  = __builtin_fmaf(sk, wg[q], g1);
        dot = __builtin_fmaf(sk, ws[q], dot);
        float sn = __builtin_fmaf(c2, sk, -skm1);
        skm1 = sk; sk = sn;
      }
      float2 f01 = __half22float2(*(__half2*)&Y0.x);
      float2 fzg = __half22float2(*(__half2*)&Y0.y);
      acc0 = __builtin_fmaf(g1, f01.x, acc0);
      acc1 = __builtin_fmaf(g1, f01.y, acc1);
      accs += leaky(dot + fzg.x);
      c0 = c1; p0 = p1; c1 = cn; p1 = p2; Y0 = Y1; Y1 = Y2;
    }
  }
  float id = 1.0f / fmaxf((float)(bnd - a), 1.0f);
  uint2 Yg = yzg[(n << 4) + r];
  float gt = __half22float2(*(__half2*)&Yg.y).y;
  float2* xr2 = (float2*)xr;
  float2 x = xr2[(n << 4) + r];
  x.x += acc0 * id * gt;
  x.y += acc1 * id * gt;
  xr2[(n << 4) + r] = x;
  float s_new = xs[(n << 4) + r] + accs * id;
  xs[(n << 4) + r] = s_new;

  if (write_next) {
    float wmxn[16], wsan[16], wgtn[16];
#pragma unroll
    for (int q = 0; q < 16; q++) wmxn[q] = Wmixn[r * 16 + q];
#pragma unroll
    for (int q = 0; q < 16; q++) wsan[q] = Ws1n[q * 16 + r];
#pragma unroll
    for (int q = 0; q < 16; q++) wgtn[q] = Wgaten[q * 16 + r];
    float y0 = 0.f, y1 = 0.f;
    float z = bs1n[r], gtn = bgaten[r];
#pragma unroll
    for (int j = 0; j < 16; j++) {
      float xj0 = __shfl(x.x, j, 16);
      float xj1 = __shfl(x.y, j, 16);
      float sj  = __shfl(s_new, j, 16);
      y0 += wmxn[j] * xj0;
      y1 += wmxn[j] * xj1;
      z  += wsan[j] * sj;
      gtn += wgtn[j] * sj;
    }
    gtn = 1.0f / (1.0f + __expf(-gtn));
    __half2 hA = __floats2half2_rn(y0, y1);
    __half2 hB = __floats2half2_rn(z, gtn);
    uint2 w2;
    w2.x = *(unsigned int*)&hA;
    w2.y = *(unsigned int*)&hB;
    yzg_out[(n << 4) + r] = w2;
  }
}

// ---------- final rotate-out + MLP + binned graph sum (unchanged) ----------
__global__ void __launch_bounds__(128) k_final(
    int N, const float* __restrict__ xr, const float* __restrict__ xs,
    const float* __restrict__ cthn, const float* __restrict__ sthn,
    const int* __restrict__ batch,
    const float* __restrict__ W1, const float* __restrict__ b1,
    const float* __restrict__ W2, const float* __restrict__ b2,
    float* __restrict__ out) {
  __shared__ float obin[320 * 6];
  int t = threadIdx.x;
  int start = blockIdx.x * 128;
  int n = start + t;
  int b0 = batch[min(start, N - 1)];
  int span = batch[min(start + 127, N - 1)] - b0;
  bool useLds = (span < 320);
  if (useLds) for (int i = t; i < (span + 1) * 6; i += 128) obin[i] = 0.f;
  __syncthreads();

  float u[NC];
  bool act = (n < N);
  if (act) {
    float xc[48];
    const float4* xs4 = (const float4*)(xs + (size_t)n * NS);
#pragma unroll
    for (int j = 0; j < 4; j++) {
      float4 v = xs4[j];
      xc[4 * j + 0] = v.x; xc[4 * j + 1] = v.y; xc[4 * j + 2] = v.z; xc[4 * j + 3] = v.w;
    }
    float c = cthn[n], s = sthn[n];
    const float4* xr4 = (const float4*)(xr + (size_t)n * 32);
#pragma unroll
    for (int j = 0; j < 8; j++) {
      float4 v = xr4[j];
      xc[16 + 4 * j + 0] = c * v.x - s * v.y;
      xc[16 + 4 * j + 1] = s * v.x + c * v.y;
      xc[16 + 4 * j + 2] = c * v.z - s * v.w;
      xc[16 + 4 * j + 3] = s * v.z + c * v.w;
    }
#pragma unroll
    for (int q = 0; q < NC; q++) u[q] = b2[q];
    for (int h = 0; h < H1; h += 4) {
      float a0 = b1[h + 0], a1 = b1[h + 1], a2 = b1[h + 2], a3 = b1[h + 3];
#pragma unroll
      for (int q = 0; q < 48; q++) {
        float4 w = *(const float4*)(W1 + (size_t)q * H1 + h);
        float x = xc[q];
        a0 = __builtin_fmaf(x, w.x, a0);
        a1 = __builtin_fmaf(x, w.y, a1);
        a2 = __builtin_fmaf(x, w.z, a2);
        a3 = __builtin_fmaf(x, w.w, a3);
      }
      a0 = leaky(a0); a1 = leaky(a1); a2 = leaky(a2); a3 = leaky(a3);
#pragma unroll
      for (int q = 0; q < NC; q++)
        u[q] += a0 * W2[(h + 0) * 6 + q] + a1 * W2[(h + 1) * 6 + q]
              + a2 * W2[(h + 2) * 6 + q] + a3 * W2[(h + 3) * 6 + q];
    }
  }
  if (useLds) {
    if (act) {
      int rb = batch[n] - b0;
#pragma unroll
      for (int q = 0; q < NC; q++) atomicAdd(&obin[rb * 6 + q], u[q]);
    }
    __syncthreads();
    for (int i = t; i < (span + 1) * 6; i += 128) atomicAdd(&out[b0 * 6 + i], obin[i]);
  } else if (act) {
    int b = batch[n];
#pragma unroll
    for (int q = 0; q < NC; q++) atomicAdd(&out[b * 6 + q], u[q]);
  }
}

extern "C" void kernel_launch(void* const* d_in, const int* in_sizes, int n_in,
                              void* d_out, int out_size, void* d_ws, size_t ws_size,
                              hipStream_t stream) {
  const float* pos   = (const float*)d_in[0];
  const float* Wer   = (const float*)d_in[1];
  const float* wse   = (const float*)d_in[2];
  const float* bse   = (const float*)d_in[3];
  const float* Wg    = (const float*)d_in[4];
  const float* bg    = (const float*)d_in[5];
  const float* Wmix  = (const float*)d_in[6];
  const float* Wgate = (const float*)d_in[7];
  const float* bgate = (const float*)d_in[8];
  const float* Ws1   = (const float*)d_in[9];
  const float* bs1   = (const float*)d_in[10];
  const float* W1    = (const float*)d_in[11];
  const float* b1    = (const float*)d_in[12];
  const float* W2    = (const float*)d_in[13];
  const float* b2    = (const float*)d_in[14];
  const int*   ei    = (const int*)d_in[15];
  const int*   batch = (const int*)d_in[16];
  float* out = (float*)d_out;

  int N = in_sizes[0] / 2;
  int E = in_sizes[15] / 2;
  int G = out_size / NC;
  int NB = (N + 255) / 256;   // 256-row buckets (requires NB <= NBMAX)

  // ---- workspace layout (~67 MB; ebuf aliases spc) ----
  float* W = (float*)d_ws;
  size_t o = 0;
  float* gsum   = W + o; o += (size_t)2 * G;
  float* gcnt   = W + o; o += (size_t)G;
  int*   bhist  = (int*)(W + o); o += (size_t)NBMAX;
  int*   dhist  = (int*)(W + o); o += (size_t)DBINS;
  int*   dcur   = (int*)(W + o); o += (size_t)DBINS;
  size_t zero_bytes = o * 4;
  o = (o + 3) & ~(size_t)3;
  float* posc   = W + o; o += (size_t)2 * N;
  float* cthn   = W + o; o += (size_t)N;
  float* sthn   = W + o; o += (size_t)N;
  int*   off    = (int*)(W + o); o += (size_t)N + 1; o = (o + 3) & ~(size_t)3;
  int*   bbase  = (int*)(W + o); o += (size_t)NBMAX + 1;
  int*   bcur   = (int*)(W + o); o += (size_t)NBMAX;
  int*   cnt    = (int*)(W + o); o += (size_t)N;
  int*   perm   = (int*)(W + o); o += (size_t)N; o = (o + 3) & ~(size_t)3;
  int*   adj    = (int*)(W + o); o += (size_t)E; o = (o + 1) & ~(size_t)1;
  float2* spc   = (float2*)(W + o); o += (size_t)2 * E;
  long long* ebuf = (long long*)spc;   // ALIAS: ebuf dead after k_part2; spc written by k_init16
  uint2* yzgA   = (uint2*)(W + o); o += (size_t)32 * N;
  uint2* yzgB   = (uint2*)(W + o); o += (size_t)32 * N;
  float* xr     = W + o; o += (size_t)N * 32;
  float* xs     = W + o; o += (size_t)N * 16;
  (void)ws_size;

  hipMemsetAsync(d_ws, 0, zero_bytes, stream);
  hipMemsetAsync(d_out, 0, (size_t)out_size * 4, stream);

  int nbN  = (N + 255) / 256;
  int nbT  = (E + TILE - 1) / TILE;
  int nbG  = nbT > nbN ? nbT : nbN;
  int nbN16 = ((size_t)N * 16 + 255) / 256;
  int nbP  = (N + 1023) / 1024;
  int nbF  = (N + 127) / 128;

  k_gsum_bhist<<<nbG, 256, 0, stream>>>(pos, batch, N, gsum, gcnt, ei, E, bhist);
  k_center_bscan<<<nbN, 256, 0, stream>>>(pos, batch, N, E, gsum, gcnt,
                                          posc, cthn, sthn, bhist, bbase, bcur, NB);
  k_part1<<<nbT, 256, 0, stream>>>(ei, E, bcur, ebuf);
  k_part2<<<NB, 256, 0, stream>>>(bbase, N, E, ebuf, off, cnt, dhist, adj);
  k_init16<<<nbN16, 256, 0, stream>>>(N, off, adj, posc, spc, Wer, wse, bse,
                                      Wmix, Ws1, bs1, Wgate, bgate,
                                      xr, xs, yzgA);
  k_permfill<<<nbP, 1024, 0, stream>>>(N, cnt, dhist, dcur, perm);

  // layer 0: read A, write B (fused pre for layer 1)
  k_layer<<<nbN16, 256, 0, stream>>>(N, off, adj, spc, yzgA, perm,
                                     Wg, bg, Ws1, xr, xs,
                                     1, yzgB,
                                     Wmix + 256, Ws1 + 512, bs1 + 16, Wgate + 256, bgate + 16);
  // layer 1: read B, write A (fused pre for layer 2)
  k_layer<<<nbN16, 256, 0, stream>>>(N, off, adj, spc, yzgB, perm,
                                     Wg + 256, bg + 16, Ws1 + 512, xr, xs,
                                     1, yzgA,
                                     Wmix + 512, Ws1 + 1024, bs1 + 32, Wgate + 512, bgate + 32);
  // layer 2: read A, no next
  k_layer<<<nbN16, 256, 0, stream>>>(N, off, adj, spc, yzgA, perm,
                                     Wg + 512, bg + 32, Ws1 + 1024, xr, xs,
                                     0, yzgB,
                                     Wmix, Ws1, bs1, Wgate, bgate);

  k_final<<<nbF, 128, 0, stream>>>(N, xr, xs, cthn, sthn, batch, W1, b1, W2, b2, out);
}

// Round 10
// 405.004 us; speedup vs baseline: 1.5563x; 1.0184x over previous
//
#include <hip/hip_runtime.h>
#include <hip/hip_fp16.h>
#include <math.h>

#define NREP 16
#define RDIM 16
#define NS   16
#define NC   6
#define H1   144
#define DBINS 64
#define TILE 4096
#define NBMAX 512     // max 256-row buckets supported (N <= 131072)
#define P2CAP 10240   // bucket LDS adj capacity; mean bucket = 4096 edges

typedef float f2 __attribute__((ext_vector_type(2)));

static __device__ __forceinline__ float leaky(float v) { return v > 0.0f ? v : 0.01f * v; }

// ---------- fused: per-graph mean (LDS-binned) + LDS-aggregated bucket histogram ----------
__global__ void __launch_bounds__(256) k_gsum_bhist(
    const float* __restrict__ pos, const int* __restrict__ batch, int N,
    float* __restrict__ gsum, float* __restrict__ gcnt,
    const int* __restrict__ ei, int E, int* __restrict__ bhist) {
  int t = threadIdx.x;
  __shared__ int h[NBMAX];
  for (int i = t; i < NBMAX; i += 256) h[i] = 0;
  __syncthreads();
  int base = blockIdx.x * TILE;
  int lim = min(base + TILE, E);
  for (int j = base + t; j < lim; j += 256) atomicAdd(&h[ei[j] >> 8], 1);
  __syncthreads();
  for (int i = t; i < NBMAX; i += 256)
    if (h[i] > 0) atomicAdd(&bhist[i], h[i]);

  __shared__ float bx[320], by[320], bc[320];
  int start = blockIdx.x * 256;
  if (start >= N) return;
  int n = start + t;
  int b0 = batch[min(start, N - 1)];
  int span = batch[min(start + 255, N - 1)] - b0;
  bool useLds = (span < 320);
  if (useLds) {
    for (int i = t; i <= span; i += 256) { bx[i] = 0.f; by[i] = 0.f; bc[i] = 0.f; }
    __syncthreads();
    if (n < N) {
      int rb = batch[n] - b0;
      atomicAdd(&bx[rb], pos[2 * n + 0]);
      atomicAdd(&by[rb], pos[2 * n + 1]);
      atomicAdd(&bc[rb], 1.0f);
    }
    __syncthreads();
    for (int i = t; i <= span; i += 256) {
      if (bc[i] != 0.0f) {
        atomicAdd(&gsum[2 * (b0 + i) + 0], bx[i]);
        atomicAdd(&gsum[2 * (b0 + i) + 1], by[i]);
        atomicAdd(&gcnt[b0 + i], bc[i]);
      }
    }
  } else if (n < N) {
    int b = batch[n];
    atomicAdd(&gsum[2 * b + 0], pos[2 * n + 0]);
    atomicAdd(&gsum[2 * b + 1], pos[2 * n + 1]);
    atomicAdd(&gcnt[b], 1.0f);
  }
}

// ---------- center (elementwise) + block0: bucket-base scan ----------
__global__ void __launch_bounds__(256) k_center_bscan(
    const float* __restrict__ pos, const int* __restrict__ batch, int N, int E,
    const float* __restrict__ gsum, const float* __restrict__ gcnt,
    float* __restrict__ posc, float* __restrict__ cthn, float* __restrict__ sthn,
    const int* __restrict__ bhist, int* __restrict__ bbase, int* __restrict__ bcur, int NB) {
  int t = threadIdx.x;
  if (blockIdx.x == 0) {
    __shared__ int s[NBMAX];
    int v0 = (t < NB) ? bhist[t] : 0;
    int v1 = (t + 256 < NB) ? bhist[t + 256] : 0;
    s[t] = v0; s[t + 256] = v1;
    __syncthreads();
    for (int o = 1; o < NBMAX; o <<= 1) {
      int a0 = (t >= o) ? s[t - o] : 0;
      int a1 = s[t + 256 - o];
      __syncthreads();
      s[t] += a0; s[t + 256] += a1;
      __syncthreads();
    }
    if (t < NB)       { int ex = s[t] - v0;       bbase[t] = ex;       bcur[t] = ex; }
    if (t + 256 < NB) { int ex = s[t + 256] - v1; bbase[t + 256] = ex; bcur[t + 256] = ex; }
    if (t == 0) bbase[NB] = E;
  }
  int i = blockIdx.x * 256 + t;
  if (i < N) {
    int b = batch[i];
    float invc = 1.0f / fmaxf(gcnt[b], 1.0f);
    float px = pos[2 * i + 0] - gsum[2 * b + 0] * invc;
    float py = pos[2 * i + 1] - gsum[2 * b + 1] * invc;
    posc[2 * i + 0] = px;
    posc[2 * i + 1] = py;
    float r = sqrtf(px * px + py * py);
    if (r > 0.0f) { cthn[i] = px / r; sthn[i] = py / r; }
    else          { cthn[i] = 1.0f;  sthn[i] = 0.0f; }
  }
}

// ---------- CSR build pass 1: bucket-partition edges by row>>8 ----------
__global__ void __launch_bounds__(256) k_part1(
    const int* __restrict__ ei, int E,
    int* __restrict__ bcur, long long* __restrict__ ebuf) {
  __shared__ int hist[NBMAX], lofs[NBMAX], gbase[NBMAX], pc[NBMAX];
  __shared__ long long stg[TILE];
  __shared__ unsigned short bkt[TILE];
  int t = threadIdx.x;
  int base = blockIdx.x * TILE;
  int cntt = min(TILE, E - base);
  for (int i = t; i < NBMAX; i += 256) { hist[i] = 0; pc[i] = 0; }
  __syncthreads();
  int r[16], c[16];
#pragma unroll
  for (int i = 0; i < 16; i++) {
    int e = base + t + i * 256;
    r[i] = -1;
    if (e < E) {
      r[i] = ei[e];
      c[i] = ei[E + e];
      atomicAdd(&hist[r[i] >> 8], 1);
    }
  }
  __syncthreads();
  lofs[t] = hist[t]; lofs[t + 256] = hist[t + 256];
  __syncthreads();
  for (int o = 1; o < NBMAX; o <<= 1) {
    int a0 = (t >= o) ? lofs[t - o] : 0;
    int a1 = lofs[t + 256 - o];
    __syncthreads();
    lofs[t] += a0; lofs[t + 256] += a1;
    __syncthreads();
  }
  int e0 = lofs[t] - hist[t], e1 = lofs[t + 256] - hist[t + 256];
  __syncthreads();
  lofs[t] = e0; lofs[t + 256] = e1;
  __syncthreads();
  for (int i = t; i < NBMAX; i += 256)
    if (hist[i] > 0) gbase[i] = atomicAdd(&bcur[i], hist[i]);
  __syncthreads();
#pragma unroll
  for (int i = 0; i < 16; i++) {
    if (r[i] >= 0) {
      int b = r[i] >> 8;
      int l = lofs[b] + atomicAdd(&pc[b], 1);
      stg[l] = ((long long)r[i] << 32) | (unsigned int)c[i];
      bkt[l] = (unsigned short)b;
    }
  }
  __syncthreads();
  for (int j = t; j < cntt; j += 256) {
    int b = bkt[j];
    ebuf[gbase[b] + (j - lofs[b])] = stg[j];
  }
}

// ---------- lean pass 2: per-bucket row-hist + local scan (off/cnt/dhist) + in-LDS adj ----------
__global__ void __launch_bounds__(256) k_part2(
    const int* __restrict__ bbase, int N, int E,
    const long long* __restrict__ ebuf,
    int* __restrict__ off, int* __restrict__ cnt, int* __restrict__ dhist,
    int* __restrict__ adj) {
  __shared__ int lcnt[256], loff[256], lcur[256];
  __shared__ int lh[DBINS];
  __shared__ int ladj[P2CAP];
  int t = threadIdx.x;
  int b = blockIdx.x;
  int r0 = b << 8;
  int abeg = bbase[b];
  int aend = bbase[b + 1];
  int sz = aend - abeg;
  bool haveRow = (r0 + t < N);
  lcnt[t] = 0;
  if (t < DBINS) lh[t] = 0;
  __syncthreads();
  for (int j = abeg + t; j < aend; j += 256)
    atomicAdd(&lcnt[(int)(ebuf[j] >> 32) - r0], 1);
  __syncthreads();
  int v = lcnt[t];
  loff[t] = v;
  __syncthreads();
  for (int o = 1; o < 256; o <<= 1) {
    int u = (t >= o) ? loff[t - o] : 0;
    __syncthreads();
    loff[t] += u;
    __syncthreads();
  }
  int myoff = loff[t] - v;
  __syncthreads();
  loff[t] = myoff;
  lcur[t] = myoff;
  if (haveRow) {
    off[r0 + t] = abeg + myoff;
    cnt[r0 + t] = v;
    atomicAdd(&lh[min(v, DBINS - 1)], 1);
  }
  if (t == 0 && r0 + 256 >= N) off[N] = E;
  __syncthreads();
  if (t < DBINS && lh[t] > 0) atomicAdd(&dhist[t], lh[t]);
  if (sz <= P2CAP) {
    for (int j = abeg + t; j < aend; j += 256) {
      long long p = ebuf[j];
      int cl = (int)(unsigned int)(p & 0xffffffffLL);
      int rr = (int)(p >> 32) - r0;
      ladj[atomicAdd(&lcur[rr], 1)] = cl;
    }
    __syncthreads();
    for (int j = t; j < sz; j += 256) adj[abeg + j] = ladj[j];
  } else {
    for (int j = abeg + t; j < aend; j += 256) {
      long long p = ebuf[j];
      int cl = (int)(unsigned int)(p & 0xffffffffLL);
      int rr = (int)(p >> 32) - r0;
      adj[abeg + atomicAdd(&lcur[rr], 1)] = cl;
    }
  }
}

// ---------- fused node init + per-edge trig fill + layer-0 pre ----------
__global__ void __launch_bounds__(256) k_init16(
    int N, const int* __restrict__ off, const int* __restrict__ adj,
    const float* __restrict__ posc, float2* __restrict__ spc,
    const float* __restrict__ Wer, const float* __restrict__ wse, const float* __restrict__ bse,
    const float* __restrict__ Wmix, const float* __restrict__ Ws1, const float* __restrict__ bs1,
    const float* __restrict__ Wgate, const float* __restrict__ bgate,
    float* __restrict__ xr, float* __restrict__ xs, uint2* __restrict__ yzg) {
  int idx = blockIdx.x * 256 + threadIdx.x;
  int n = idx >> 4, r = idx & 15;
  if (n >= N) return;
  int a = off[n], b = off[n + 1];
  float px = posc[2 * n + 0], py = posc[2 * n + 1];
  float C = 0.f, S = 0.f, D = 0.f;
  for (int k = a + r; k < b; k += 16) {
    int cl = adj[k];
    float dx = px - posc[2 * cl + 0];
    float dy = py - posc[2 * cl + 1];
    float d = sqrtf(dx * dx + dy * dy);
    float sp, cp;
    sincospif(d, &sp, &cp);
    float spp = 1.41421356237309515f * sp / (d + 1e-8f);
    spc[k] = make_float2(spp, 2.0f * cp);
    if (d > 0.0f) {
      float inv = 1.0f / d;
      C += dx * inv;
      S += dy * inv;
    } else {
      C += 1.0f;
    }
    D += d;
  }
#pragma unroll
  for (int o = 1; o < 16; o <<= 1) {
    C += __shfl_xor(C, o, 16);
    S += __shfl_xor(S, o, 16);
    D += __shfl_xor(D, o, 16);
  }
  float id = 1.0f / fmaxf((float)(b - a), 1.0f);
  C *= id; S *= id;
  float dm = D * id;
  float w0 = Wer[2 * r], w1 = Wer[2 * r + 1];
  float2 x;
  x.x = C * w0 - S * w1;
  x.y = S * w0 + C * w1;
  ((float2*)xr)[(size_t)n * 16 + r] = x;
  float s_new = leaky(dm * wse[r] + bse[r]);
  xs[(size_t)n * 16 + r] = s_new;

  float wmxn[16], wsan[16], wgtn[16];
#pragma unroll
  for (int q = 0; q < 16; q++) wmxn[q] = Wmix[r * 16 + q];
#pragma unroll
  for (int q = 0; q < 16; q++) wsan[q] = Ws1[q * 16 + r];
#pragma unroll
  for (int q = 0; q < 16; q++) wgtn[q] = Wgate[q * 16 + r];
  float y0 = 0.f, y1 = 0.f;
  float z = bs1[r], gtn = bgate[r];
#pragma unroll
  for (int j = 0; j < 16; j++) {
    float xj0 = __shfl(x.x, j, 16);
    float xj1 = __shfl(x.y, j, 16);
    float sj  = __shfl(s_new, j, 16);
    y0 += wmxn[j] * xj0;
    y1 += wmxn[j] * xj1;
    z  += wsan[j] * sj;
    gtn += wgtn[j] * sj;
  }
  gtn = 1.0f / (1.0f + __expf(-gtn));
  __half2 hA = __floats2half2_rn(y0, y1);
  __half2 hB = __floats2half2_rn(z, gtn);
  uint2 w2;
  w2.x = *(unsigned int*)&hA;
  w2.y = *(unsigned int*)&hB;
  yzg[(size_t)n * 16 + r] = w2;
}

// ---------- degree-sort perm fill ----------
__global__ void k_permfill(int N, const int* __restrict__ cnt,
                           const int* __restrict__ dhist,
                           int* __restrict__ dcur, int* __restrict__ perm) {
  __shared__ int sd[DBINS], dbase[DBINS];
  __shared__ int lh[DBINS], base[DBINS];
  int t = threadIdx.x;
  int dv = 0;
  if (t < DBINS) { dv = dhist[t]; sd[t] = dv; lh[t] = 0; }
  __syncthreads();
  for (int o = 1; o < DBINS; o <<= 1) {
    int u = (t >= o && t < DBINS) ? sd[t - o] : 0;
    __syncthreads();
    if (t < DBINS) sd[t] += u;
    __syncthreads();
  }
  if (t < DBINS) dbase[t] = sd[t] - dv;
  __syncthreads();
  int i = blockIdx.x * 1024 + t;
  int b = 0, lr = 0;
  if (i < N) {
    b = min(cnt[i], DBINS - 1);
    lr = atomicAdd(&lh[b], 1);
  }
  __syncthreads();
  if (t < DBINS && lh[t] > 0) base[t] = dbase[t] + atomicAdd(&dcur[t], lh[t]);
  __syncthreads();
  if (i < N) perm[base[b] + lr] = i;
}

// ---------- EqBlock layer: PACKED 2-edge inner loop (v_pk_fma_f32) + fused next-layer pre ----------
// r9 counters: VALUBusy 75.8%, hbm 28% -> issue-limited. The 48 scalar FMAs/edge pair up
// across two edges into f2 (ext_vector) ops so the compiler emits packed v_pk_fma_f32
// (2 FMA/instr — CDNA4's full fp32 rate). Clamped final pair + uniform guard handles odd
// degree; <=1 scalar remainder edge.
__global__ void __launch_bounds__(256) k_layer(
    int N, const int* __restrict__ off,
    const int* __restrict__ adj, const float2* __restrict__ spc,
    const uint2* __restrict__ yzg, const int* __restrict__ perm,
    const float* __restrict__ Wg, const float* __restrict__ bg,
    const float* __restrict__ Ws1,   // this layer; demb rows are 16..31
    float* xr, float* xs,
    int write_next, uint2* __restrict__ yzg_out,
    const float* __restrict__ Wmixn, const float* __restrict__ Ws1n,
    const float* __restrict__ bs1n,
    const float* __restrict__ Wgaten, const float* __restrict__ bgaten) {
  int idx = blockIdx.x * 256 + threadIdx.x;
  int g = idx >> 4, r = idx & 15;
  if (g >= N) return;
  int n = perm[g];
  float wg[16], ws[16];
#pragma unroll
  for (int q = 0; q < 16; q++) wg[q] = Wg[q * 16 + r];
#pragma unroll
  for (int q = 0; q < 16; q++) ws[q] = Ws1[(16 + q) * 16 + r];
  float bgr = bg[r];

  int a = off[n], bnd = off[n + 1];
  float acc0 = 0.f, acc1 = 0.f, accs = 0.f;

#define PAIR_BODY(PA, PB, YA, YB, SECOND_OK)                                   \
  {                                                                            \
    f2 sk; sk.x = (PA).x; sk.y = (PB).x;                                       \
    f2 c2v; c2v.x = (PA).y; c2v.y = (PB).y;                                    \
    f2 skm1 = {0.f, 0.f};                                                      \
    f2 g1; g1.x = bgr; g1.y = bgr;                                             \
    f2 dt = {0.f, 0.f};                                                        \
    _Pragma("unroll")                                                          \
    for (int q = 0; q < RDIM; q++) {                                           \
      f2 wgq; wgq.x = wg[q]; wgq.y = wg[q];                                    \
      f2 wsq; wsq.x = ws[q]; wsq.y = ws[q];                                    \
      g1 = __builtin_elementwise_fma(sk, wgq, g1);                             \
      dt = __builtin_elementwise_fma(sk, wsq, dt);                             \
      f2 sn = __builtin_elementwise_fma(c2v, sk, -skm1);                       \
      skm1 = sk; sk = sn;                                                      \
    }                                                                          \
    float2 f01a = __half22float2(*(__half2*)&(YA).x);                          \
    float2 fzga = __half22float2(*(__half2*)&(YA).y);                          \
    acc0 = __builtin_fmaf(g1.x, f01a.x, acc0);                                 \
    acc1 = __builtin_fmaf(g1.x, f01a.y, acc1);                                 \
    accs += leaky(dt.x + fzga.x);                                              \
    if (SECOND_OK) {                                                           \
      float2 f01b = __half22float2(*(__half2*)&(YB).x);                        \
      float2 fzgb = __half22float2(*(__half2*)&(YB).y);                        \
      acc0 = __builtin_fmaf(g1.y, f01b.x, acc0);                               \
      acc1 = __builtin_fmaf(g1.y, f01b.y, acc1);                               \
      accs += leaky(dt.y + fzgb.x);                                            \
    }                                                                          \
  }

  int k = a;
  if (a < bnd) {
    int last = bnd - 1;
    // current pair (k, min(k+1,last)) fully loaded
    int    ca = adj[k],               cb = adj[min(k + 1, last)];
    float2 pa = spc[k],               pb = spc[min(k + 1, last)];
    uint2  Ya = yzg[(ca << 4) + r],   Yb = yzg[(cb << 4) + r];
    for (; k + 3 < bnd; k += 2) {
      // prefetch next pair (k+2, k+3) — provably in range
      int    cn0 = adj[k + 2],             cn1 = adj[k + 3];
      float2 pn0 = spc[k + 2],             pn1 = spc[k + 3];
      uint2  Yn0 = yzg[(cn0 << 4) + r],    Yn1 = yzg[(cn1 << 4) + r];
      PAIR_BODY(pa, pb, Ya, Yb, true);
      ca = cn0; cb = cn1; pa = pn0; pb = pn1; Ya = Yn0; Yb = Yn1;
    }
    // final pair in registers: second element valid iff k+1 <= last (uniform per 16-lane group)
    PAIR_BODY(pa, pb, Ya, Yb, (k + 1 <= last));
    k += 2;
  }
  // scalar remainder (<=1 edge)
  for (; k < bnd; k++) {
    int cl = adj[k];
    float2 p = spc[k];
    uint2 Y = yzg[(cl << 4) + r];
    float skm1 = 0.f, sk = p.x, c2 = p.y;
    float g1 = bgr, dot = 0.f;
#pragma unroll
    for (int q = 0; q < RDIM; q++) {
      g1  = __builtin_fmaf(sk, wg[q], g1);
      dot = __builtin_fmaf(sk, ws[q], dot);
      float sn = __builtin_fmaf(c2, sk, -skm1);
      skm1 = sk; sk = sn;
    }
    float2 f01 = __half22float2(*(__half2*)&Y.x);
    float2 fzg = __half22float2(*(__half2*)&Y.y);
    acc0 = __builtin_fmaf(g1, f01.x, acc0);
    acc1 = __builtin_fmaf(g1, f01.y, acc1);
    accs += leaky(dot + fzg.x);
  }
#undef PAIR_BODY

  float id = 1.0f / fmaxf((float)(bnd - a), 1.0f);
  uint2 Yg = yzg[(n << 4) + r];
  float gt = __half22float2(*(__half2*)&Yg.y).y;
  float2* xr2 = (float2*)xr;
  float2 x = xr2[(n << 4) + r];
  x.x += acc0 * id * gt;
  x.y += acc1 * id * gt;
  xr2[(n << 4) + r] = x;
  float s_new = xs[(n << 4) + r] + accs * id;
  xs[(n << 4) + r] = s_new;

  if (write_next) {
    float wmxn[16], wsan[16], wgtn[16];
#pragma unroll
    for (int q = 0; q < 16; q++) wmxn[q] = Wmixn[r * 16 + q];
#pragma unroll
    for (int q = 0; q < 16; q++) wsan[q] = Ws1n[q * 16 + r];
#pragma unroll
    for (int q = 0; q < 16; q++) wgtn[q] = Wgaten[q * 16 + r];
    float y0 = 0.f, y1 = 0.f;
    float z = bs1n[r], gtn = bgaten[r];
#pragma unroll
    for (int j = 0; j < 16; j++) {
      float xj0 = __shfl(x.x, j, 16);
      float xj1 = __shfl(x.y, j, 16);
      float sj  = __shfl(s_new, j, 16);
      y0 += wmxn[j] * xj0;
      y1 += wmxn[j] * xj1;
      z  += wsan[j] * sj;
      gtn += wgtn[j] * sj;
    }
    gtn = 1.0f / (1.0f + __expf(-gtn));
    __half2 hA = __floats2half2_rn(y0, y1);
    __half2 hB = __floats2half2_rn(z, gtn);
    uint2 w2;
    w2.x = *(unsigned int*)&hA;
    w2.y = *(unsigned int*)&hB;
    yzg_out[(n << 4) + r] = w2;
  }
}

// ---------- final rotate-out + MLP + binned graph sum (unchanged) ----------
__global__ void __launch_bounds__(128) k_final(
    int N, const float* __restrict__ xr, const float* __restrict__ xs,
    const float* __restrict__ cthn, const float* __restrict__ sthn,
    const int* __restrict__ batch,
    const float* __restrict__ W1, const float* __restrict__ b1,
    const float* __restrict__ W2, const float* __restrict__ b2,
    float* __restrict__ out) {
  __shared__ float obin[320 * 6];
  int t = threadIdx.x;
  int start = blockIdx.x * 128;
  int n = start + t;
  int b0 = batch[min(start, N - 1)];
  int span = batch[min(start + 127, N - 1)] - b0;
  bool useLds = (span < 320);
  if (useLds) for (int i = t; i < (span + 1) * 6; i += 128) obin[i] = 0.f;
  __syncthreads();

  float u[NC];
  bool act = (n < N);
  if (act) {
    float xc[48];
    const float4* xs4 = (const float4*)(xs + (size_t)n * NS);
#pragma unroll
    for (int j = 0; j < 4; j++) {
      float4 v = xs4[j];
      xc[4 * j + 0] = v.x; xc[4 * j + 1] = v.y; xc[4 * j + 2] = v.z; xc[4 * j + 3] = v.w;
    }
    float c = cthn[n], s = sthn[n];
    const float4* xr4 = (const float4*)(xr + (size_t)n * 32);
#pragma unroll
    for (int j = 0; j < 8; j++) {
      float4 v = xr4[j];
      xc[16 + 4 * j + 0] = c * v.x - s * v.y;
      xc[16 + 4 * j + 1] = s * v.x + c * v.y;
      xc[16 + 4 * j + 2] = c * v.z - s * v.w;
      xc[16 + 4 * j + 3] = s * v.z + c * v.w;
    }
#pragma unroll
    for (int q = 0; q < NC; q++) u[q] = b2[q];
    for (int h = 0; h < H1; h += 4) {
      float a0 = b1[h + 0], a1 = b1[h + 1], a2 = b1[h + 2], a3 = b1[h + 3];
#pragma unroll
      for (int q = 0; q < 48; q++) {
        float4 w = *(const float4*)(W1 + (size_t)q * H1 + h);
        float x = xc[q];
        a0 = __builtin_fmaf(x, w.x, a0);
        a1 = __builtin_fmaf(x, w.y, a1);
        a2 = __builtin_fmaf(x, w.z, a2);
        a3 = __builtin_fmaf(x, w.w, a3);
      }
      a0 = leaky(a0); a1 = leaky(a1); a2 = leaky(a2); a3 = leaky(a3);
#pragma unroll
      for (int q = 0; q < NC; q++)
        u[q] += a0 * W2[(h + 0) * 6 + q] + a1 * W2[(h + 1) * 6 + q]
              + a2 * W2[(h + 2) * 6 + q] + a3 * W2[(h + 3) * 6 + q];
    }
  }
  if (useLds) {
    if (act) {
      int rb = batch[n] - b0;
#pragma unroll
      for (int q = 0; q < NC; q++) atomicAdd(&obin[rb * 6 + q], u[q]);
    }
    __syncthreads();
    for (int i = t; i < (span + 1) * 6; i += 128) atomicAdd(&out[b0 * 6 + i], obin[i]);
  } else if (act) {
    int b = batch[n];
#pragma unroll
    for (int q = 0; q < NC; q++) atomicAdd(&out[b * 6 + q], u[q]);
  }
}

extern "C" void kernel_launch(void* const* d_in, const int* in_sizes, int n_in,
                              void* d_out, int out_size, void* d_ws, size_t ws_size,
                              hipStream_t stream) {
  const float* pos   = (const float*)d_in[0];
  const float* Wer   = (const float*)d_in[1];
  const float* wse   = (const float*)d_in[2];
  const float* bse   = (const float*)d_in[3];
  const float* Wg    = (const float*)d_in[4];
  const float* bg    = (const float*)d_in[5];
  const float* Wmix  = (const float*)d_in[6];
  const float* Wgate = (const float*)d_in[7];
  const float* bgate = (const float*)d_in[8];
  const float* Ws1   = (const float*)d_in[9];
  const float* bs1   = (const float*)d_in[10];
  const float* W1    = (const float*)d_in[11];
  const float* b1    = (const float*)d_in[12];
  const float* W2    = (const float*)d_in[13];
  const float* b2    = (const float*)d_in[14];
  const int*   ei    = (const int*)d_in[15];
  const int*   batch = (const int*)d_in[16];
  float* out = (float*)d_out;

  int N = in_sizes[0] / 2;
  int E = in_sizes[15] / 2;
  int G = out_size / NC;
  int NB = (N + 255) / 256;   // 256-row buckets (requires NB <= NBMAX)

  // ---- workspace layout (~67 MB; ebuf aliases spc) ----
  float* W = (float*)d_ws;
  size_t o = 0;
  float* gsum   = W + o; o += (size_t)2 * G;
  float* gcnt   = W + o; o += (size_t)G;
  int*   bhist  = (int*)(W + o); o += (size_t)NBMAX;
  int*   dhist  = (int*)(W + o); o += (size_t)DBINS;
  int*   dcur   = (int*)(W + o); o += (size_t)DBINS;
  size_t zero_bytes = o * 4;
  o = (o + 3) & ~(size_t)3;
  float* posc   = W + o; o += (size_t)2 * N;
  float* cthn   = W + o; o += (size_t)N;
  float* sthn   = W + o; o += (size_t)N;
  int*   off    = (int*)(W + o); o += (size_t)N + 1; o = (o + 3) & ~(size_t)3;
  int*   bbase  = (int*)(W + o); o += (size_t)NBMAX + 1;
  int*   bcur   = (int*)(W + o); o += (size_t)NBMAX;
  int*   cnt    = (int*)(W + o); o += (size_t)N;
  int*   perm   = (int*)(W + o); o += (size_t)N; o = (o + 3) & ~(size_t)3;
  int*   adj    = (int*)(W + o); o += (size_t)E; o = (o + 1) & ~(size_t)1;
  float2* spc   = (float2*)(W + o); o += (size_t)2 * E;
  long long* ebuf = (long long*)spc;   // ALIAS: ebuf dead after k_part2; spc written by k_init16
  uint2* yzgA   = (uint2*)(W + o); o += (size_t)32 * N;
  uint2* yzgB   = (uint2*)(W + o); o += (size_t)32 * N;
  float* xr     = W + o; o += (size_t)N * 32;
  float* xs     = W + o; o += (size_t)N * 16;
  (void)ws_size;

  hipMemsetAsync(d_ws, 0, zero_bytes, stream);
  hipMemsetAsync(d_out, 0, (size_t)out_size * 4, stream);

  int nbN  = (N + 255) / 256;
  int nbT  = (E + TILE - 1) / TILE;
  int nbG  = nbT > nbN ? nbT : nbN;
  int nbN16 = ((size_t)N * 16 + 255) / 256;
  int nbP  = (N + 1023) / 1024;
  int nbF  = (N + 127) / 128;

  k_gsum_bhist<<<nbG, 256, 0, stream>>>(pos, batch, N, gsum, gcnt, ei, E, bhist);
  k_center_bscan<<<nbN, 256, 0, stream>>>(pos, batch, N, E, gsum, gcnt,
                                          posc, cthn, sthn, bhist, bbase, bcur, NB);
  k_part1<<<nbT, 256, 0, stream>>>(ei, E, bcur, ebuf);
  k_part2<<<NB, 256, 0, stream>>>(bbase, N, E, ebuf, off, cnt, dhist, adj);
  k_init16<<<nbN16, 256, 0, stream>>>(N, off, adj, posc, spc, Wer, wse, bse,
                                      Wmix, Ws1, bs1, Wgate, bgate,
                                      xr, xs, yzgA);
  k_permfill<<<nbP, 1024, 0, stream>>>(N, cnt, dhist, dcur, perm);

  // layer 0: read A, write B (fused pre for layer 1)
  k_layer<<<nbN16, 256, 0, stream>>>(N, off, adj, spc, yzgA, perm,
                                     Wg, bg, Ws1, xr, xs,
                                     1, yzgB,
                                     Wmix + 256, Ws1 + 512, bs1 + 16, Wgate + 256, bgate + 16);
  // layer 1: read B, write A (fused pre for layer 2)
  k_layer<<<nbN16, 256, 0, stream>>>(N, off, adj, spc, yzgB, perm,
                                     Wg + 256, bg + 16, Ws1 + 512, xr, xs,
                                     1, yzgA,
                                     Wmix + 512, Ws1 + 1024, bs1 + 32, Wgate + 512, bgate + 32);
  // layer 2: read A, no next
  k_layer<<<nbN16, 256, 0, stream>>>(N, off, adj, spc, yzgA, perm,
                                     Wg + 512, bg + 32, Ws1 + 1024, xr, xs,
                                     0, yzgB,
                                     Wmix, Ws1, bs1, Wgate, bgate);

  k_final<<<nbF, 128, 0, stream>>>(N, xr, xs, cthn, sthn, batch, W1, b1, W2, b2, out);
}